// Round 4
// baseline (2824.781 us; speedup 1.0000x reference)
//
#include <hip/hip_runtime.h>

// BRITS-style RNN (B=4096, T=256, D=36, H=64) on gfx950.
// R4: 512 blocks x 512 threads (8 waves), ROWS=8 rows/block (M=16 MFMA half-padded)
// -> 2 blocks/CU for cross-block latency hiding. 3 barriers/step (was 4): hist_W
// replicated across all 16 B-cols of the vx aux MFMA so each S-wave lane holds
// vx[row] in regs (no vx LDS round-trip). Waves 0-3 "G": gates r,z,n for dims
// 16w..16w+15 (h in regs). Waves 4-6 "S": vx + gamma/feat/comb GEMMs + impute.
// Wave 7: staging only. Frag-linear LDS layout -> conflict-free ds_read_b128.

#define Bsz 4096
#define Tn  256
#define Dn  36
#define ROWS 8
#define EPSf 1e-5f
#define VMST 38

using f32x4 = __attribute__((ext_vector_type(4))) float;
using s8    = __attribute__((ext_vector_type(8))) short;

__device__ __forceinline__ short f2bf(float x) {
  unsigned u = __float_as_uint(x);
  unsigned r = (u + 0x7FFFu + ((u >> 16) & 1u)) >> 16;  // RNE
  return (short)r;
}
__device__ __forceinline__ float sigf(float x) { return 1.f / (1.f + __expf(-x)); }
__device__ __forceinline__ float tanhfast(float x) { return 1.f - 2.f / (1.f + __expf(2.f * x)); }
// fragment-linear offset for element (row, k) of an MFMA A-tile (16 rows, bf16):
// lane = ((k%32)/8)*16 + row, addr = (k/32)*512 + lane*8 + k%8
__device__ __forceinline__ int fragoff(int row, int k) {
  return ((k >> 5) << 9) + (((k >> 3) & 3) << 7) + (row << 3) + (k & 7);
}

// ---------------- prepass: rmsum[t] = 1/(sum(masks[:,t,:]) + EPS) -------------
__global__ void msum_k(const float4* __restrict__ masks4, float* __restrict__ rmsum) {
  int t = blockIdx.x;
  float s = 0.f;
  for (int r = threadIdx.x; r < Bsz; r += 256) {
    const float4* mp = masks4 + ((size_t)r * Tn + t) * 9;
    #pragma unroll
    for (int j = 0; j < 9; ++j) { float4 v = mp[j]; s += v.x + v.y + v.z + v.w; }
  }
  __shared__ float red[256];
  red[threadIdx.x] = s;
  __syncthreads();
  for (int k = 128; k > 0; k >>= 1) {
    if (threadIdx.x < k) red[threadIdx.x] += red[threadIdx.x + k];
    __syncthreads();
  }
  if (threadIdx.x == 0) rmsum[t] = 1.f / (red[0] + EPSf);
}

// ---------------- main ---------------------------------------------------------
__global__ __launch_bounds__(512, 4) void brits_main(
    const float* __restrict__ values, const float* __restrict__ masks,
    const float* __restrict__ deltas, const float* __restrict__ label,
    const float* __restrict__ is_train,
    const float* __restrict__ W_ih, const float* __restrict__ W_hh,
    const float* __restrict__ b_ih, const float* __restrict__ b_hh,
    const float* __restrict__ hist_W, const float* __restrict__ hist_b,
    const float* __restrict__ feat_W, const float* __restrict__ feat_b,
    const float* __restrict__ decay_W, const float* __restrict__ decay_b,
    const float* __restrict__ comb_W, const float* __restrict__ comb_b,
    const float* __restrict__ out_W, const float* __restrict__ out_b,
    float* __restrict__ out, const float* __restrict__ rmsum,
    float* __restrict__ ws_acc /* [0] il, [1] cls, [2] wsum */) {

  __shared__ float2 vm_s[16 * VMST];     // (value, mask); rows ROWS..15 stay (0,0)
  __shared__ float  red_s[512];
  __shared__ float  red16[16];
  __shared__ short  dbuf[1024];          // delta,  K=64  (frag-linear; unstaged = 0)
  __shared__ short  vcbuf[1024];         // vc1,    K=64  (frag-linear)
  __shared__ short  hbuf[1024];          // h bf16, K=64  (frag-linear)
  __shared__ short  xbuf[2048];          // [mask(0:36)|gamma(36:72)|vc2(72:108)|0], K=128

  const int tid  = threadIdx.x;
  const int w    = tid >> 6;        // wave 0..7
  const int lane = tid & 63;
  const int lc   = lane & 15;
  const int r4   = lane >> 4;
  const bool isG = (w < 4);
  const int row0 = blockIdx.x * ROWS;
  const int k0b  = r4 * 8;

  // ---- weight fragments (persistent VGPRs, role-overlaid) ----
  // G:   bfrag[g*4+kt] = W_ih (xbuf k-space remap), bfrag[12+g*2+kt] = W_hh
  // S46: bfrag[0..1]=decay, [2..3]=feat(zero diag), [4..6]=comb, [7..8]=hist (all cols)
  s8 bfrag[18];
  #pragma unroll
  for (int i = 0; i < 18; ++i) bfrag[i] = (s8)(short)0;

  float br = 0.f, bz = 0.f, bin_ = 0.f, bhn = 0.f, ow = 0.f;
  float db = 0.f, fb = 0.f, cbv = 0.f;
  int nsm = 0, dim = 0;
  const float histb = hist_b[0];

  if (isG) {
    dim = 16 * w + lc;
    #pragma unroll
    for (int g = 0; g < 3; ++g) {
      const int n = 64 * g + dim;
      #pragma unroll
      for (int kt = 0; kt < 4; ++kt) {
        s8 f;
        #pragma unroll
        for (int e = 0; e < 8; ++e) {
          int xk = k0b + 32 * kt + e;
          // xbuf k-space: [mask(0:36)|gamma(36:72)|vc2(72:108)|pad]
          // W_ih cols:    [vc(0:36)|mask(36:72)|gamma(72:108)]
          float wv = 0.f;
          if (xk < 72) wv = W_ih[n * 108 + 36 + xk];        // mask & gamma
          else if (xk < 108) wv = W_ih[n * 108 + xk - 72];  // vc2
          f[e] = f2bf(wv);
        }
        bfrag[g * 4 + kt] = f;
      }
      #pragma unroll
      for (int kt = 0; kt < 2; ++kt) {
        s8 f;
        #pragma unroll
        for (int e = 0; e < 8; ++e) f[e] = f2bf(W_hh[n * 64 + k0b + 32 * kt + e]);
        bfrag[12 + g * 2 + kt] = f;
      }
    }
    br   = b_ih[dim] + b_hh[dim];
    bz   = b_ih[64 + dim] + b_hh[64 + dim];
    bin_ = b_ih[128 + dim];
    bhn  = b_hh[128 + dim];
    ow   = out_W[dim];
  } else if (w < 7) {
    nsm = 16 * (w - 4) + lc;
    const bool act = (nsm < Dn);
    #pragma unroll
    for (int kt = 0; kt < 2; ++kt) {
      s8 fd, ff, fh;
      #pragma unroll
      for (int e = 0; e < 8; ++e) {
        int k = k0b + 32 * kt + e;
        fd[e] = f2bf((act && k < Dn) ? decay_W[nsm * Dn + k] : 0.f);
        ff[e] = f2bf((act && k < Dn && k != nsm) ? feat_W[nsm * Dn + k] : 0.f);
        fh[e] = f2bf(hist_W[k]);          // replicated across ALL 16 cols
      }
      bfrag[kt] = fd; bfrag[2 + kt] = ff; bfrag[7 + kt] = fh;
    }
    #pragma unroll
    for (int kt = 0; kt < 3; ++kt) {
      s8 f;
      #pragma unroll
      for (int e = 0; e < 8; ++e) {
        int xk = k0b + 32 * kt + e;
        // comb input [gamma(0:36)|mask(36:72)]; xbuf = [mask(0:36)|gamma(36:72)|...]
        float wv = 0.f;
        if (act) {
          if (xk < 36) wv = comb_W[nsm * 72 + 36 + xk];       // mask part
          else if (xk < 72) wv = comb_W[nsm * 72 + xk - 36];  // gamma part
        }
        f[e] = f2bf(wv);
      }
      bfrag[4 + kt] = f;
    }
    db  = act ? decay_b[nsm] : 0.f;
    fb  = act ? feat_b[nsm] : 0.f;
    cbv = act ? comb_b[nsm] : 0.f;
  }

  // ---- S staging geometry: 288 slots (8 rows x 36 cols) over 256 S-threads ----
  const int sidx = tid - 256;
  size_t pbase[2] = {0, 0};
  int vmoff[2] = {0, 0}, foff[2] = {0, 0};
  bool pval[2] = {false, false};
  if (!isG) {
    #pragma unroll
    for (int j = 0; j < 2; ++j) {
      int slot = sidx + 256 * j;
      pval[j] = (slot < ROWS * Dn);
      if (pval[j]) {
        int pr = slot / Dn;
        int pc = slot - pr * Dn;
        pbase[j] = ((size_t)(row0 + pr) * Tn) * Dn + pc;
        vmoff[j] = pr * VMST + pc;
        foff[j]  = fragoff(pr, pc);       // dbuf (K-geom); xbuf mask region same k
      }
    }
  }

  // ---- init LDS ----
  for (int i = tid; i < 1024; i += 512) { dbuf[i] = 0; vcbuf[i] = 0; hbuf[i] = 0; }
  for (int i = tid; i < 2048; i += 512) xbuf[i] = 0;
  for (int i = tid; i < 16 * VMST; i += 512) vm_s[i] = make_float2(0.f, 0.f);
  __syncthreads();

  // ---- prologue: stage t=0, prefetch t=1 ----
  float pv[2] = {0.f, 0.f}, pm[2] = {0.f, 0.f}, pd[2] = {0.f, 0.f};
  if (!isG) {
    #pragma unroll
    for (int j = 0; j < 2; ++j) if (pval[j]) {
      float v = values[pbase[j]], m = masks[pbase[j]], d = deltas[pbase[j]];
      vm_s[vmoff[j]] = make_float2(v, m);
      dbuf[foff[j]] = f2bf(d);
      xbuf[foff[j]] = f2bf(m);
    }
    #pragma unroll
    for (int j = 0; j < 2; ++j) if (pval[j]) {
      pv[j] = values[pbase[j] + Dn]; pm[j] = masks[pbase[j] + Dn]; pd[j] = deltas[pbase[j] + Dn];
    }
  }
  float hreg[4] = {0.f, 0.f, 0.f, 0.f};
  float lacc[4] = {0.f, 0.f, 0.f, 0.f};
  float vxq[4] = {0.f, 0.f, 0.f, 0.f};
  float il = 0.f;
  f32x4 A0 = {0,0,0,0}, A1 = {0,0,0,0}, A2 = {0,0,0,0}, A3 = {0,0,0,0};
  __syncthreads();

  #pragma unroll 1
  for (int t = 0; t < Tn; ++t) {
    const float srm = rmsum[t];

    // ---- P1: G: gh + gi-kt0 | S46: vx(replicated) + gamma + vc1 + il_x ----
    if (isG) {
      A0 = (f32x4){0,0,0,0}; A1 = (f32x4){0,0,0,0}; A2 = (f32x4){0,0,0,0}; A3 = (f32x4){0,0,0,0};
      #pragma unroll
      for (int kt = 0; kt < 2; ++kt) {
        s8 a = *(const s8*)&hbuf[kt * 512 + lane * 8];
        A0 = __builtin_amdgcn_mfma_f32_16x16x32_bf16(a, bfrag[12 + kt], A0, 0, 0, 0);
        A1 = __builtin_amdgcn_mfma_f32_16x16x32_bf16(a, bfrag[14 + kt], A1, 0, 0, 0);
        A3 = __builtin_amdgcn_mfma_f32_16x16x32_bf16(a, bfrag[16 + kt], A3, 0, 0, 0);
      }
      {
        s8 a = *(const s8*)&xbuf[lane * 8];
        A0 = __builtin_amdgcn_mfma_f32_16x16x32_bf16(a, bfrag[0], A0, 0, 0, 0);
        A1 = __builtin_amdgcn_mfma_f32_16x16x32_bf16(a, bfrag[4], A1, 0, 0, 0);
        A2 = __builtin_amdgcn_mfma_f32_16x16x32_bf16(a, bfrag[8], A2, 0, 0, 0);
      }
    } else if (w < 7) {
      f32x4 X = {0,0,0,0}, Gm = {0,0,0,0};
      #pragma unroll
      for (int kt = 0; kt < 2; ++kt) {
        s8 ah = *(const s8*)&hbuf[kt * 512 + lane * 8];
        X  = __builtin_amdgcn_mfma_f32_16x16x32_bf16(ah, bfrag[7 + kt], X, 0, 0, 0);
        s8 ad = *(const s8*)&dbuf[kt * 512 + lane * 8];
        Gm = __builtin_amdgcn_mfma_f32_16x16x32_bf16(ad, bfrag[kt], Gm, 0, 0, 0);
      }
      #pragma unroll
      for (int q = 0; q < 4; ++q) vxq[q] = X[q] + histb;
      if (nsm < Dn) {
        const int gb = fragoff(0, 36 + nsm);
        const int vb1 = fragoff(0, nsm);
        #pragma unroll
        for (int q = 0; q < 4; ++q) {
          int rr = r4 * 4 + q;
          float g = __expf(-fmaxf(Gm[q] + db, 0.f));
          xbuf[gb + rr * 8] = f2bf(g);
          float2 vm = vm_s[rr * VMST + nsm];
          il += srm * fabsf(vxq[q] - vm.x) * vm.y;
          vcbuf[vb1 + rr * 8] = f2bf(vm.y * vm.x + (1.f - vm.y) * vxq[q]);
        }
      }
    }
    __syncthreads();  // b1: gamma + vc1 ready

    // ---- P2: G: gi-kt1 | S46: feat + comb GEMMs + impute chain + vc2 ----
    if (isG) {
      s8 a = *(const s8*)&xbuf[512 + lane * 8];
      A0 = __builtin_amdgcn_mfma_f32_16x16x32_bf16(a, bfrag[1], A0, 0, 0, 0);
      A1 = __builtin_amdgcn_mfma_f32_16x16x32_bf16(a, bfrag[5], A1, 0, 0, 0);
      A2 = __builtin_amdgcn_mfma_f32_16x16x32_bf16(a, bfrag[9], A2, 0, 0, 0);
    } else if (w < 7) {
      f32x4 Z = {0,0,0,0}, Bc = {0,0,0,0};
      #pragma unroll
      for (int kt = 0; kt < 2; ++kt) {
        s8 av = *(const s8*)&vcbuf[kt * 512 + lane * 8];
        Z = __builtin_amdgcn_mfma_f32_16x16x32_bf16(av, bfrag[2 + kt], Z, 0, 0, 0);
      }
      #pragma unroll
      for (int kt = 0; kt < 3; ++kt) {
        s8 ac = *(const s8*)&xbuf[kt * 512 + lane * 8];
        Bc = __builtin_amdgcn_mfma_f32_16x16x32_bf16(ac, bfrag[4 + kt], Bc, 0, 0, 0);
      }
      if (nsm < Dn) {
        const int vb = fragoff(0, 72 + nsm);
        #pragma unroll
        for (int q = 0; q < 4; ++q) {
          int rr = r4 * 4 + q;
          float beta = sigf(Bc[q] + cbv);
          float vz = Z[q] + fb;
          float2 vm = vm_s[rr * VMST + nsm];
          il += srm * fabsf(vz - vm.x) * vm.y;
          float vh = vz * beta + vxq[q] * (1.f - beta);
          il += srm * fabsf(vh - vm.x) * vm.y;
          float vc2 = vm.y * vm.x + (1.f - vm.y) * vh;
          if (rr < ROWS) out[1 + ((size_t)(row0 + rr) * Tn + t) * Dn + nsm] = vc2;
          xbuf[vb + rr * 8] = f2bf(vc2);
        }
      }
    }
    __syncthreads();  // b2: vc2 ready

    // ---- P3: G: gi-kt2/3 + GRU update -> hbuf | S: stage t+1, prefetch t+2 ----
    if (isG) {
      #pragma unroll
      for (int kt = 2; kt < 4; ++kt) {
        s8 a = *(const s8*)&xbuf[kt * 512 + lane * 8];
        A0 = __builtin_amdgcn_mfma_f32_16x16x32_bf16(a, bfrag[kt], A0, 0, 0, 0);
        A1 = __builtin_amdgcn_mfma_f32_16x16x32_bf16(a, bfrag[4 + kt], A1, 0, 0, 0);
        A2 = __builtin_amdgcn_mfma_f32_16x16x32_bf16(a, bfrag[8 + kt], A2, 0, 0, 0);
      }
      const int hb = fragoff(0, dim);
      #pragma unroll
      for (int q = 0; q < 4; ++q) {
        float rg = sigf(A0[q] + br);
        float zg = sigf(A1[q] + bz);
        float ng = tanhfast(A2[q] + bin_ + rg * (A3[q] + bhn));
        float hn = (1.f - zg) * ng + zg * hreg[q];
        hreg[q] = hn;
        lacc[q] += hn * ow;
        hbuf[hb + (r4 * 4 + q) * 8] = f2bf(hn);
      }
    } else {
      if (t + 1 < Tn) {
        #pragma unroll
        for (int j = 0; j < 2; ++j) if (pval[j]) {
          vm_s[vmoff[j]] = make_float2(pv[j], pm[j]);
          dbuf[foff[j]] = f2bf(pd[j]);
          xbuf[foff[j]] = f2bf(pm[j]);
        }
      }
      if (t + 2 < Tn) {
        size_t o = (size_t)(t + 2) * Dn;
        #pragma unroll
        for (int j = 0; j < 2; ++j) if (pval[j]) {
          pv[j] = values[pbase[j] + o];
          pm[j] = masks[pbase[j] + o];
          pd[j] = deltas[pbase[j] + o];
        }
      }
    }
    __syncthreads();  // b3: end of step (hbuf + staged t+1 ready)
  }

  // ---- epilogue: reduce il, logits, pred, class loss ----
  red_s[tid] = il;
  __syncthreads();
  for (int k = 256; k > 0; k >>= 1) {
    if (tid < k) red_s[tid] += red_s[tid + k];
    __syncthreads();
  }
  if (tid == 0) atomicAdd(&ws_acc[0], red_s[0]);
  if (tid < 16) red16[tid] = 0.f;
  __syncthreads();
  if (isG && r4 < 2) {   // rows 0..7 only
    #pragma unroll
    for (int q = 0; q < 4; ++q) atomicAdd(&red16[r4 * 4 + q], lacc[q]);
  }
  __syncthreads();

  if (tid < ROWS) {
    float lg = red16[tid] / (float)Tn + out_b[0];
    int rg = row0 + tid;
    float pred = sigf(lg);
    out[1 + (size_t)Bsz * Tn * Dn + rg] = pred;
    float y = label[rg], wt = is_train[rg];
    float bce = fmaxf(lg, 0.f) - lg * y + log1pf(__expf(-fabsf(lg)));
    atomicAdd(&ws_acc[1], bce * wt);
    atomicAdd(&ws_acc[2], wt);
  }
}

// ---------------- finalize loss -------------------------------------------------
__global__ void fin_k(const float* __restrict__ ws, float* __restrict__ out) {
  out[0] = ws[1] / (ws[2] + EPSf) + ws[0] / (float)Tn;
}

extern "C" void kernel_launch(void* const* d_in, const int* in_sizes, int n_in,
                              void* d_out, int out_size, void* d_ws, size_t ws_size,
                              hipStream_t stream) {
  const float* values   = (const float*)d_in[0];
  const float* masks    = (const float*)d_in[1];
  const float* deltas   = (const float*)d_in[2];
  const float* label    = (const float*)d_in[3];
  const float* is_train = (const float*)d_in[4];
  const float* W_ih     = (const float*)d_in[5];
  const float* W_hh     = (const float*)d_in[6];
  const float* b_ih     = (const float*)d_in[7];
  const float* b_hh     = (const float*)d_in[8];
  const float* hist_W   = (const float*)d_in[9];
  const float* hist_b   = (const float*)d_in[10];
  const float* feat_W   = (const float*)d_in[11];
  const float* feat_b   = (const float*)d_in[12];
  const float* decay_W  = (const float*)d_in[13];
  const float* decay_b  = (const float*)d_in[14];
  const float* comb_W   = (const float*)d_in[15];
  const float* comb_b   = (const float*)d_in[16];
  const float* out_W    = (const float*)d_in[17];
  const float* out_b    = (const float*)d_in[18];

  float* ws = (float*)d_ws;
  float* rmsum = ws + 4;
  float* out = (float*)d_out;

  hipMemsetAsync(d_ws, 0, 16, stream);
  msum_k<<<Tn, 256, 0, stream>>>((const float4*)masks, rmsum);
  brits_main<<<Bsz / ROWS, 512, 0, stream>>>(
      values, masks, deltas, label, is_train, W_ih, W_hh, b_ih, b_hh,
      hist_W, hist_b, feat_W, feat_b, decay_W, decay_b, comb_W, comb_b,
      out_W, out_b, out, rmsum, ws);
  fin_k<<<1, 1, 0, stream>>>(ws, out);
}

// Round 5
// 898.082 us; speedup vs baseline: 3.1453x; 3.1453x over previous
//
#include <hip/hip_runtime.h>

// BRITS-style RNN (B=4096, T=256, D=36, H=64) on gfx950.
// R5: R4 structure (512 blocks x 512 threads, ROWS=8, 3 barriers/step) but with
// __launch_bounds__(512,2): R4's (512,4) clamped VGPRs to 64 -> weight-fragment
// spill to scratch (hbm_bytes 3.8e8->9.1e8, 2825us). At the natural ~96-110 VGPRs
// (<=128) the HW already co-schedules 2 blocks/CU (occupancy ladder halves at
// 64/128/256), giving cross-block latency hiding without any register coercion.
// Waves 0-3 "G": gates r,z,n for dims 16w..16w+15 (h in regs, W_ih/W_hh in VGPRs).
// Waves 4-6 "S": vx (hist_W replicated across all 16 B-cols -> vx in regs),
// gamma/feat/comb GEMMs, imputation chain. Wave 7: staging only.
// Frag-linear LDS layout -> conflict-free ds_read_b128.

#define Bsz 4096
#define Tn  256
#define Dn  36
#define ROWS 8
#define EPSf 1e-5f
#define VMST 38

using f32x4 = __attribute__((ext_vector_type(4))) float;
using s8    = __attribute__((ext_vector_type(8))) short;

__device__ __forceinline__ short f2bf(float x) {
  unsigned u = __float_as_uint(x);
  unsigned r = (u + 0x7FFFu + ((u >> 16) & 1u)) >> 16;  // RNE
  return (short)r;
}
__device__ __forceinline__ float sigf(float x) { return 1.f / (1.f + __expf(-x)); }
__device__ __forceinline__ float tanhfast(float x) { return 1.f - 2.f / (1.f + __expf(2.f * x)); }
// fragment-linear offset for element (row, k) of an MFMA A-tile (16 rows, bf16):
// lane = ((k%32)/8)*16 + row, addr = (k/32)*512 + lane*8 + k%8
__device__ __forceinline__ int fragoff(int row, int k) {
  return ((k >> 5) << 9) + (((k >> 3) & 3) << 7) + (row << 3) + (k & 7);
}

// ---------------- prepass: rmsum[t] = 1/(sum(masks[:,t,:]) + EPS) -------------
__global__ void msum_k(const float4* __restrict__ masks4, float* __restrict__ rmsum) {
  int t = blockIdx.x;
  float s = 0.f;
  for (int r = threadIdx.x; r < Bsz; r += 256) {
    const float4* mp = masks4 + ((size_t)r * Tn + t) * 9;
    #pragma unroll
    for (int j = 0; j < 9; ++j) { float4 v = mp[j]; s += v.x + v.y + v.z + v.w; }
  }
  __shared__ float red[256];
  red[threadIdx.x] = s;
  __syncthreads();
  for (int k = 128; k > 0; k >>= 1) {
    if (threadIdx.x < k) red[threadIdx.x] += red[threadIdx.x + k];
    __syncthreads();
  }
  if (threadIdx.x == 0) rmsum[t] = 1.f / (red[0] + EPSf);
}

// ---------------- main ---------------------------------------------------------
__global__ __launch_bounds__(512, 2) void brits_main(
    const float* __restrict__ values, const float* __restrict__ masks,
    const float* __restrict__ deltas, const float* __restrict__ label,
    const float* __restrict__ is_train,
    const float* __restrict__ W_ih, const float* __restrict__ W_hh,
    const float* __restrict__ b_ih, const float* __restrict__ b_hh,
    const float* __restrict__ hist_W, const float* __restrict__ hist_b,
    const float* __restrict__ feat_W, const float* __restrict__ feat_b,
    const float* __restrict__ decay_W, const float* __restrict__ decay_b,
    const float* __restrict__ comb_W, const float* __restrict__ comb_b,
    const float* __restrict__ out_W, const float* __restrict__ out_b,
    float* __restrict__ out, const float* __restrict__ rmsum,
    float* __restrict__ ws_acc /* [0] il, [1] cls, [2] wsum */) {

  __shared__ float2 vm_s[16 * VMST];     // (value, mask); rows ROWS..15 stay (0,0)
  __shared__ float  red_s[512];
  __shared__ float  red16[16];
  __shared__ short  dbuf[1024];          // delta,  K=64  (frag-linear; unstaged = 0)
  __shared__ short  vcbuf[1024];         // vc1,    K=64  (frag-linear)
  __shared__ short  hbuf[1024];          // h bf16, K=64  (frag-linear)
  __shared__ short  xbuf[2048];          // [mask(0:36)|gamma(36:72)|vc2(72:108)|0], K=128

  const int tid  = threadIdx.x;
  const int w    = tid >> 6;        // wave 0..7
  const int lane = tid & 63;
  const int lc   = lane & 15;
  const int r4   = lane >> 4;
  const bool isG = (w < 4);
  const int row0 = blockIdx.x * ROWS;
  const int k0b  = r4 * 8;

  // ---- weight fragments (persistent VGPRs, role-overlaid) ----
  // G:   bfrag[g*4+kt] = W_ih (xbuf k-space remap), bfrag[12+g*2+kt] = W_hh
  // S46: bfrag[0..1]=decay, [2..3]=feat(zero diag), [4..6]=comb, [7..8]=hist (all cols)
  s8 bfrag[18];
  #pragma unroll
  for (int i = 0; i < 18; ++i) bfrag[i] = (s8)(short)0;

  float br = 0.f, bz = 0.f, bin_ = 0.f, bhn = 0.f, ow = 0.f;
  float db = 0.f, fb = 0.f, cbv = 0.f;
  int nsm = 0, dim = 0;
  const float histb = hist_b[0];

  if (isG) {
    dim = 16 * w + lc;
    #pragma unroll
    for (int g = 0; g < 3; ++g) {
      const int n = 64 * g + dim;
      #pragma unroll
      for (int kt = 0; kt < 4; ++kt) {
        s8 f;
        #pragma unroll
        for (int e = 0; e < 8; ++e) {
          int xk = k0b + 32 * kt + e;
          // xbuf k-space: [mask(0:36)|gamma(36:72)|vc2(72:108)|pad]
          // W_ih cols:    [vc(0:36)|mask(36:72)|gamma(72:108)]
          float wv = 0.f;
          if (xk < 72) wv = W_ih[n * 108 + 36 + xk];        // mask & gamma
          else if (xk < 108) wv = W_ih[n * 108 + xk - 72];  // vc2
          f[e] = f2bf(wv);
        }
        bfrag[g * 4 + kt] = f;
      }
      #pragma unroll
      for (int kt = 0; kt < 2; ++kt) {
        s8 f;
        #pragma unroll
        for (int e = 0; e < 8; ++e) f[e] = f2bf(W_hh[n * 64 + k0b + 32 * kt + e]);
        bfrag[12 + g * 2 + kt] = f;
      }
    }
    br   = b_ih[dim] + b_hh[dim];
    bz   = b_ih[64 + dim] + b_hh[64 + dim];
    bin_ = b_ih[128 + dim];
    bhn  = b_hh[128 + dim];
    ow   = out_W[dim];
  } else if (w < 7) {
    nsm = 16 * (w - 4) + lc;
    const bool act = (nsm < Dn);
    #pragma unroll
    for (int kt = 0; kt < 2; ++kt) {
      s8 fd, ff, fh;
      #pragma unroll
      for (int e = 0; e < 8; ++e) {
        int k = k0b + 32 * kt + e;
        fd[e] = f2bf((act && k < Dn) ? decay_W[nsm * Dn + k] : 0.f);
        ff[e] = f2bf((act && k < Dn && k != nsm) ? feat_W[nsm * Dn + k] : 0.f);
        fh[e] = f2bf(hist_W[k]);          // replicated across ALL 16 cols
      }
      bfrag[kt] = fd; bfrag[2 + kt] = ff; bfrag[7 + kt] = fh;
    }
    #pragma unroll
    for (int kt = 0; kt < 3; ++kt) {
      s8 f;
      #pragma unroll
      for (int e = 0; e < 8; ++e) {
        int xk = k0b + 32 * kt + e;
        // comb input [gamma(0:36)|mask(36:72)]; xbuf = [mask(0:36)|gamma(36:72)|...]
        float wv = 0.f;
        if (act) {
          if (xk < 36) wv = comb_W[nsm * 72 + 36 + xk];       // mask part
          else if (xk < 72) wv = comb_W[nsm * 72 + xk - 36];  // gamma part
        }
        f[e] = f2bf(wv);
      }
      bfrag[4 + kt] = f;
    }
    db  = act ? decay_b[nsm] : 0.f;
    fb  = act ? feat_b[nsm] : 0.f;
    cbv = act ? comb_b[nsm] : 0.f;
  }

  // ---- S staging geometry: 288 slots (8 rows x 36 cols) over 256 S-threads ----
  const int sidx = tid - 256;
  size_t pbase[2] = {0, 0};
  int vmoff[2] = {0, 0}, foff[2] = {0, 0};
  bool pval[2] = {false, false};
  if (!isG) {
    #pragma unroll
    for (int j = 0; j < 2; ++j) {
      int slot = sidx + 256 * j;
      pval[j] = (slot < ROWS * Dn);
      if (pval[j]) {
        int pr = slot / Dn;
        int pc = slot - pr * Dn;
        pbase[j] = ((size_t)(row0 + pr) * Tn) * Dn + pc;
        vmoff[j] = pr * VMST + pc;
        foff[j]  = fragoff(pr, pc);       // dbuf (K-geom); xbuf mask region same k
      }
    }
  }

  // ---- init LDS ----
  for (int i = tid; i < 1024; i += 512) { dbuf[i] = 0; vcbuf[i] = 0; hbuf[i] = 0; }
  for (int i = tid; i < 2048; i += 512) xbuf[i] = 0;
  for (int i = tid; i < 16 * VMST; i += 512) vm_s[i] = make_float2(0.f, 0.f);
  __syncthreads();

  // ---- prologue: stage t=0, prefetch t=1 ----
  float pv[2] = {0.f, 0.f}, pm[2] = {0.f, 0.f}, pd[2] = {0.f, 0.f};
  if (!isG) {
    #pragma unroll
    for (int j = 0; j < 2; ++j) if (pval[j]) {
      float v = values[pbase[j]], m = masks[pbase[j]], d = deltas[pbase[j]];
      vm_s[vmoff[j]] = make_float2(v, m);
      dbuf[foff[j]] = f2bf(d);
      xbuf[foff[j]] = f2bf(m);
    }
    #pragma unroll
    for (int j = 0; j < 2; ++j) if (pval[j]) {
      pv[j] = values[pbase[j] + Dn]; pm[j] = masks[pbase[j] + Dn]; pd[j] = deltas[pbase[j] + Dn];
    }
  }
  float hreg[4] = {0.f, 0.f, 0.f, 0.f};
  float lacc[4] = {0.f, 0.f, 0.f, 0.f};
  float vxq[4] = {0.f, 0.f, 0.f, 0.f};
  float il = 0.f;
  f32x4 A0 = {0,0,0,0}, A1 = {0,0,0,0}, A2 = {0,0,0,0}, A3 = {0,0,0,0};
  __syncthreads();

  #pragma unroll 1
  for (int t = 0; t < Tn; ++t) {
    const float srm = rmsum[t];

    // ---- P1: G: gh + gi-kt0 | S46: vx(replicated) + gamma + vc1 + il_x ----
    if (isG) {
      A0 = (f32x4){0,0,0,0}; A1 = (f32x4){0,0,0,0}; A2 = (f32x4){0,0,0,0}; A3 = (f32x4){0,0,0,0};
      #pragma unroll
      for (int kt = 0; kt < 2; ++kt) {
        s8 a = *(const s8*)&hbuf[kt * 512 + lane * 8];
        A0 = __builtin_amdgcn_mfma_f32_16x16x32_bf16(a, bfrag[12 + kt], A0, 0, 0, 0);
        A1 = __builtin_amdgcn_mfma_f32_16x16x32_bf16(a, bfrag[14 + kt], A1, 0, 0, 0);
        A3 = __builtin_amdgcn_mfma_f32_16x16x32_bf16(a, bfrag[16 + kt], A3, 0, 0, 0);
      }
      {
        s8 a = *(const s8*)&xbuf[lane * 8];
        A0 = __builtin_amdgcn_mfma_f32_16x16x32_bf16(a, bfrag[0], A0, 0, 0, 0);
        A1 = __builtin_amdgcn_mfma_f32_16x16x32_bf16(a, bfrag[4], A1, 0, 0, 0);
        A2 = __builtin_amdgcn_mfma_f32_16x16x32_bf16(a, bfrag[8], A2, 0, 0, 0);
      }
    } else if (w < 7) {
      f32x4 X = {0,0,0,0}, Gm = {0,0,0,0};
      #pragma unroll
      for (int kt = 0; kt < 2; ++kt) {
        s8 ah = *(const s8*)&hbuf[kt * 512 + lane * 8];
        X  = __builtin_amdgcn_mfma_f32_16x16x32_bf16(ah, bfrag[7 + kt], X, 0, 0, 0);
        s8 ad = *(const s8*)&dbuf[kt * 512 + lane * 8];
        Gm = __builtin_amdgcn_mfma_f32_16x16x32_bf16(ad, bfrag[kt], Gm, 0, 0, 0);
      }
      #pragma unroll
      for (int q = 0; q < 4; ++q) vxq[q] = X[q] + histb;
      if (nsm < Dn) {
        const int gb = fragoff(0, 36 + nsm);
        const int vb1 = fragoff(0, nsm);
        #pragma unroll
        for (int q = 0; q < 4; ++q) {
          int rr = r4 * 4 + q;
          float g = __expf(-fmaxf(Gm[q] + db, 0.f));
          xbuf[gb + rr * 8] = f2bf(g);
          float2 vm = vm_s[rr * VMST + nsm];
          il += srm * fabsf(vxq[q] - vm.x) * vm.y;
          vcbuf[vb1 + rr * 8] = f2bf(vm.y * vm.x + (1.f - vm.y) * vxq[q]);
        }
      }
    }
    __syncthreads();  // b1: gamma + vc1 ready

    // ---- P2: G: gi-kt1 | S46: feat + comb GEMMs + impute chain + vc2 ----
    if (isG) {
      s8 a = *(const s8*)&xbuf[512 + lane * 8];
      A0 = __builtin_amdgcn_mfma_f32_16x16x32_bf16(a, bfrag[1], A0, 0, 0, 0);
      A1 = __builtin_amdgcn_mfma_f32_16x16x32_bf16(a, bfrag[5], A1, 0, 0, 0);
      A2 = __builtin_amdgcn_mfma_f32_16x16x32_bf16(a, bfrag[9], A2, 0, 0, 0);
    } else if (w < 7) {
      f32x4 Z = {0,0,0,0}, Bc = {0,0,0,0};
      #pragma unroll
      for (int kt = 0; kt < 2; ++kt) {
        s8 av = *(const s8*)&vcbuf[kt * 512 + lane * 8];
        Z = __builtin_amdgcn_mfma_f32_16x16x32_bf16(av, bfrag[2 + kt], Z, 0, 0, 0);
      }
      #pragma unroll
      for (int kt = 0; kt < 3; ++kt) {
        s8 ac = *(const s8*)&xbuf[kt * 512 + lane * 8];
        Bc = __builtin_amdgcn_mfma_f32_16x16x32_bf16(ac, bfrag[4 + kt], Bc, 0, 0, 0);
      }
      if (nsm < Dn) {
        const int vb = fragoff(0, 72 + nsm);
        #pragma unroll
        for (int q = 0; q < 4; ++q) {
          int rr = r4 * 4 + q;
          float beta = sigf(Bc[q] + cbv);
          float vz = Z[q] + fb;
          float2 vm = vm_s[rr * VMST + nsm];
          il += srm * fabsf(vz - vm.x) * vm.y;
          float vh = vz * beta + vxq[q] * (1.f - beta);
          il += srm * fabsf(vh - vm.x) * vm.y;
          float vc2 = vm.y * vm.x + (1.f - vm.y) * vh;
          if (rr < ROWS) out[1 + ((size_t)(row0 + rr) * Tn + t) * Dn + nsm] = vc2;
          xbuf[vb + rr * 8] = f2bf(vc2);
        }
      }
    }
    __syncthreads();  // b2: vc2 ready

    // ---- P3: G: gi-kt2/3 + GRU update -> hbuf | S: stage t+1, prefetch t+2 ----
    if (isG) {
      #pragma unroll
      for (int kt = 2; kt < 4; ++kt) {
        s8 a = *(const s8*)&xbuf[kt * 512 + lane * 8];
        A0 = __builtin_amdgcn_mfma_f32_16x16x32_bf16(a, bfrag[kt], A0, 0, 0, 0);
        A1 = __builtin_amdgcn_mfma_f32_16x16x32_bf16(a, bfrag[4 + kt], A1, 0, 0, 0);
        A2 = __builtin_amdgcn_mfma_f32_16x16x32_bf16(a, bfrag[8 + kt], A2, 0, 0, 0);
      }
      const int hb = fragoff(0, dim);
      #pragma unroll
      for (int q = 0; q < 4; ++q) {
        float rg = sigf(A0[q] + br);
        float zg = sigf(A1[q] + bz);
        float ng = tanhfast(A2[q] + bin_ + rg * (A3[q] + bhn));
        float hn = (1.f - zg) * ng + zg * hreg[q];
        hreg[q] = hn;
        lacc[q] += hn * ow;
        hbuf[hb + (r4 * 4 + q) * 8] = f2bf(hn);
      }
    } else {
      if (t + 1 < Tn) {
        #pragma unroll
        for (int j = 0; j < 2; ++j) if (pval[j]) {
          vm_s[vmoff[j]] = make_float2(pv[j], pm[j]);
          dbuf[foff[j]] = f2bf(pd[j]);
          xbuf[foff[j]] = f2bf(pm[j]);
        }
      }
      if (t + 2 < Tn) {
        size_t o = (size_t)(t + 2) * Dn;
        #pragma unroll
        for (int j = 0; j < 2; ++j) if (pval[j]) {
          pv[j] = values[pbase[j] + o];
          pm[j] = masks[pbase[j] + o];
          pd[j] = deltas[pbase[j] + o];
        }
      }
    }
    __syncthreads();  // b3: end of step (hbuf + staged t+1 ready)
  }

  // ---- epilogue: reduce il, logits, pred, class loss ----
  red_s[tid] = il;
  __syncthreads();
  for (int k = 256; k > 0; k >>= 1) {
    if (tid < k) red_s[tid] += red_s[tid + k];
    __syncthreads();
  }
  if (tid == 0) atomicAdd(&ws_acc[0], red_s[0]);
  if (tid < 16) red16[tid] = 0.f;
  __syncthreads();
  if (isG && r4 < 2) {   // rows 0..7 only
    #pragma unroll
    for (int q = 0; q < 4; ++q) atomicAdd(&red16[r4 * 4 + q], lacc[q]);
  }
  __syncthreads();

  if (tid < ROWS) {
    float lg = red16[tid] / (float)Tn + out_b[0];
    int rg = row0 + tid;
    float pred = sigf(lg);
    out[1 + (size_t)Bsz * Tn * Dn + rg] = pred;
    float y = label[rg], wt = is_train[rg];
    float bce = fmaxf(lg, 0.f) - lg * y + log1pf(__expf(-fabsf(lg)));
    atomicAdd(&ws_acc[1], bce * wt);
    atomicAdd(&ws_acc[2], wt);
  }
}

// ---------------- finalize loss -------------------------------------------------
__global__ void fin_k(const float* __restrict__ ws, float* __restrict__ out) {
  out[0] = ws[1] / (ws[2] + EPSf) + ws[0] / (float)Tn;
}

extern "C" void kernel_launch(void* const* d_in, const int* in_sizes, int n_in,
                              void* d_out, int out_size, void* d_ws, size_t ws_size,
                              hipStream_t stream) {
  const float* values   = (const float*)d_in[0];
  const float* masks    = (const float*)d_in[1];
  const float* deltas   = (const float*)d_in[2];
  const float* label    = (const float*)d_in[3];
  const float* is_train = (const float*)d_in[4];
  const float* W_ih     = (const float*)d_in[5];
  const float* W_hh     = (const float*)d_in[6];
  const float* b_ih     = (const float*)d_in[7];
  const float* b_hh     = (const float*)d_in[8];
  const float* hist_W   = (const float*)d_in[9];
  const float* hist_b   = (const float*)d_in[10];
  const float* feat_W   = (const float*)d_in[11];
  const float* feat_b   = (const float*)d_in[12];
  const float* decay_W  = (const float*)d_in[13];
  const float* decay_b  = (const float*)d_in[14];
  const float* comb_W   = (const float*)d_in[15];
  const float* comb_b   = (const float*)d_in[16];
  const float* out_W    = (const float*)d_in[17];
  const float* out_b    = (const float*)d_in[18];

  float* ws = (float*)d_ws;
  float* rmsum = ws + 4;
  float* out = (float*)d_out;

  hipMemsetAsync(d_ws, 0, 16, stream);
  msum_k<<<Tn, 256, 0, stream>>>((const float4*)masks, rmsum);
  brits_main<<<Bsz / ROWS, 512, 0, stream>>>(
      values, masks, deltas, label, is_train, W_ih, W_hh, b_ih, b_hh,
      hist_W, hist_b, feat_W, feat_b, decay_W, decay_b, comb_W, comb_b,
      out_W, out_b, out, rmsum, ws);
  fin_k<<<1, 1, 0, stream>>>(ws, out);
}

// Round 6
// 705.409 us; speedup vs baseline: 4.0045x; 1.2731x over previous
//
#include <hip/hip_runtime.h>
#include <hip/hip_bf16.h>

// BRITS-style RNN (B=4096, T=256, D=36, H=64) on gfx950.
// R6: merged-role 256-thread blocks (4 waves), ROWS=8, 512 blocks -> 2 blocks/CU
// co-resident in ONE generation (per-CU VGPR pool ~1024 wave-allocs: 8 waves x
// <=128 VGPR fits; R5's 8-wave blocks at 96 VGPR could not fit 2x).
// Wave w: gates r,z,n for dims 16w..16w+15 (wih/dec/feat in VGPRs) AND S-tile w
// (waves 0-2: vx via replicated-hist MFMA, gamma/feat/comb, impute chain).
// whh/comb/hist B-frags live in LDS (streamed ds_read_b128) to stay <=128 VGPR.
// 3 barriers/step (R5 schedule). Frag-linear LDS -> conflict-free MFMA reads.
// VALU diet: __float2bfloat16 (1-instr cvt), float4 staging, packed LDS writes.

#define Bsz 4096
#define Tn  256
#define Dn  36
#define ROWS 8
#define EPSf 1e-5f
#define VMST 38

using f32x4 = __attribute__((ext_vector_type(4))) float;
using s8    = __attribute__((ext_vector_type(8))) short;

__device__ __forceinline__ short f2bf(float x) {
  return (short)__bfloat16_as_ushort(__float2bfloat16(x));
}
__device__ __forceinline__ float sigf(float x) { return 1.f / (1.f + __expf(-x)); }
__device__ __forceinline__ float tanhfast(float x) { return 1.f - 2.f / (1.f + __expf(2.f * x)); }
// fragment-linear offset for element (row, k) of an MFMA A-tile (16 rows, bf16):
// lane = ((k%32)/8)*16 + row, addr = (k/32)*512 + lane*8 + k%8  (shorts)
__device__ __forceinline__ int fragoff(int row, int k) {
  return ((k >> 5) << 9) + (((k >> 3) & 3) << 7) + (row << 3) + (k & 7);
}

// ---------------- prepass: rmsum[t] = 1/(sum(masks[:,t,:]) + EPS) -------------
__global__ void msum_k(const float4* __restrict__ masks4, float* __restrict__ rmsum) {
  int t = blockIdx.x;
  float s = 0.f;
  for (int r = threadIdx.x; r < Bsz; r += 256) {
    const float4* mp = masks4 + ((size_t)r * Tn + t) * 9;
    #pragma unroll
    for (int j = 0; j < 9; ++j) { float4 v = mp[j]; s += v.x + v.y + v.z + v.w; }
  }
  __shared__ float red[256];
  red[threadIdx.x] = s;
  __syncthreads();
  for (int k = 128; k > 0; k >>= 1) {
    if (threadIdx.x < k) red[threadIdx.x] += red[threadIdx.x + k];
    __syncthreads();
  }
  if (threadIdx.x == 0) rmsum[t] = 1.f / (red[0] + EPSf);
}

// ---------------- main ---------------------------------------------------------
__global__ __launch_bounds__(256, 4) void brits_main(
    const float* __restrict__ values, const float* __restrict__ masks,
    const float* __restrict__ deltas, const float* __restrict__ label,
    const float* __restrict__ is_train,
    const float* __restrict__ W_ih, const float* __restrict__ W_hh,
    const float* __restrict__ b_ih, const float* __restrict__ b_hh,
    const float* __restrict__ hist_W, const float* __restrict__ hist_b,
    const float* __restrict__ feat_W, const float* __restrict__ feat_b,
    const float* __restrict__ decay_W, const float* __restrict__ decay_b,
    const float* __restrict__ comb_W, const float* __restrict__ comb_b,
    const float* __restrict__ out_W, const float* __restrict__ out_b,
    float* __restrict__ out, const float* __restrict__ rmsum,
    float* __restrict__ ws_acc /* [0] il, [1] cls, [2] wsum */) {

  __shared__ __align__(16) float2 vm_s[16 * VMST];  // (value,mask); rows 8..15 stay 0
  __shared__ float  red_s[256];
  __shared__ float  red16[16];
  __shared__ __align__(16) short dbuf[1024];   // delta K=64 frag-linear ([36,64)=0)
  __shared__ __align__(16) short vcbuf[1024];  // vc1 K=64 frag-linear
  __shared__ __align__(16) short hbuf[1024];   // h bf16 K=64 frag-linear
  __shared__ __align__(16) short xbuf[2048];   // [mask|gamma|vc2|pad] K=128
  __shared__ __align__(16) short whh_l[24 * 512];  // [w][g][kt] B-frags, 24KB
  __shared__ __align__(16) short comb_l[9 * 512];  // [w][kt] B-frags, 9KB
  __shared__ __align__(16) short hist_l[2 * 512];  // [kt] shared B-frags, 2KB

  const int tid  = threadIdx.x;
  const int w    = tid >> 6;        // wave 0..3
  const int lane = tid & 63;
  const int lc   = lane & 15;
  const int r4   = lane >> 4;
  const int row0 = blockIdx.x * ROWS;
  const int k0b  = r4 * 8;
  const int lw8  = lane * 8;

  // ---- persistent VGPR weights: wih(12), dec(2), feat(2) ----
  s8 wih[12];
  s8 dec2[2], feat2[2];
  const int dim = 16 * w + lc;
  const int nsm = dim;                         // S col (waves 0-2, < 36)
  const bool sw = (w < 3);
  const bool act = sw && (nsm < Dn);

  #pragma unroll
  for (int g = 0; g < 3; ++g) {
    const int n = 64 * g + dim;
    #pragma unroll
    for (int kt = 0; kt < 4; ++kt) {
      s8 f;
      #pragma unroll
      for (int e = 0; e < 8; ++e) {
        int xk = k0b + 32 * kt + e;
        // xbuf k-space [mask(0:36)|gamma(36:72)|vc2(72:108)|pad]
        // W_ih cols    [vc(0:36)|mask(36:72)|gamma(72:108)]
        float wv = 0.f;
        if (xk < 72) wv = W_ih[n * 108 + 36 + xk];
        else if (xk < 108) wv = W_ih[n * 108 + xk - 72];
        f[e] = f2bf(wv);
      }
      wih[g * 4 + kt] = f;
    }
  }
  #pragma unroll
  for (int kt = 0; kt < 2; ++kt) {
    s8 fd, ff;
    #pragma unroll
    for (int e = 0; e < 8; ++e) {
      int k = k0b + 32 * kt + e;
      fd[e] = f2bf((act && k < Dn) ? decay_W[nsm * Dn + k] : 0.f);
      ff[e] = f2bf((act && k < Dn && k != nsm) ? feat_W[nsm * Dn + k] : 0.f);
    }
    dec2[kt] = fd; feat2[kt] = ff;
  }

  // ---- LDS-resident weights: whh (per wave), comb (waves 0-2), hist (shared) ----
  #pragma unroll
  for (int g = 0; g < 3; ++g) {
    const int n = 64 * g + dim;
    #pragma unroll
    for (int kt = 0; kt < 2; ++kt) {
      s8 f;
      #pragma unroll
      for (int e = 0; e < 8; ++e) f[e] = f2bf(W_hh[n * 64 + k0b + 32 * kt + e]);
      *(s8*)&whh_l[(w * 6 + g * 2 + kt) * 512 + lw8] = f;
    }
  }
  if (sw) {
    #pragma unroll
    for (int kt = 0; kt < 3; ++kt) {
      s8 f;
      #pragma unroll
      for (int e = 0; e < 8; ++e) {
        int xk = k0b + 32 * kt + e;
        // comb input [gamma(0:36)|mask(36:72)]; xbuf k-space [mask|gamma|...]
        float wv = 0.f;
        if (act) {
          if (xk < 36) wv = comb_W[nsm * 72 + 36 + xk];
          else if (xk < 72) wv = comb_W[nsm * 72 + xk - 36];
        }
        f[e] = f2bf(wv);
      }
      *(s8*)&comb_l[(w * 3 + kt) * 512 + lw8] = f;
    }
  } else {
    #pragma unroll
    for (int kt = 0; kt < 2; ++kt) {
      s8 f;
      #pragma unroll
      for (int e = 0; e < 8; ++e) f[e] = f2bf(hist_W[k0b + 32 * kt + e]);  // all cols
      *(s8*)&hist_l[kt * 512 + lw8] = f;
    }
  }

  // per-lane biases
  const float db   = act ? decay_b[nsm] : 0.f;
  const float fb   = act ? feat_b[nsm] : 0.f;
  const float cbv  = act ? comb_b[nsm] : 0.f;
  const float br   = b_ih[dim] + b_hh[dim];
  const float bz   = b_ih[64 + dim] + b_hh[64 + dim];
  const float bin_ = b_ih[128 + dim];
  const float bhn  = b_hh[128 + dim];
  const float ow   = out_W[dim];
  const float histb = hist_b[0];

  // write offsets
  const int gb  = fragoff(0, 36 + (nsm < Dn ? nsm : 0));
  const int vb1 = fragoff(0, (nsm < Dn ? nsm : 0));
  const int vb  = fragoff(0, 72 + (nsm < Dn ? nsm : 0));
  const int hb  = fragoff(0, dim);

  // ---- staging geometry: 72 slots (8 rows x 9 quads), lanes 0..17 per wave ----
  const bool stg = (lane < 18);
  const int srow = 2 * w + lane / 9;        // 0..7
  const int squad = lane % 9;
  const size_t sbase = ((size_t)(row0 + srow) * Tn) * Dn + squad * 4;
  const int sfo = fragoff(srow, squad * 4); // dbuf/xbuf contiguous 4-short slot
  const int svo = srow * VMST + squad * 4;  // vm_s float2 index

  // ---- init LDS ----
  for (int i = tid; i < 1024; i += 256) { dbuf[i] = 0; vcbuf[i] = 0; hbuf[i] = 0; }
  for (int i = tid; i < 2048; i += 256) xbuf[i] = 0;
  for (int i = tid; i < 16 * VMST; i += 256) vm_s[i] = make_float2(0.f, 0.f);
  __syncthreads();

  // ---- prologue: stage t=0, prefetch t=1 ----
  float4 pv4 = {0,0,0,0}, pm4 = {0,0,0,0}, pd4 = {0,0,0,0};
  if (stg) {
    float4 v0 = *(const float4*)&values[sbase];
    float4 m0 = *(const float4*)&masks[sbase];
    float4 d0 = *(const float4*)&deltas[sbase];
    *(float4*)&vm_s[svo]     = make_float4(v0.x, m0.x, v0.y, m0.y);
    *(float4*)&vm_s[svo + 2] = make_float4(v0.z, m0.z, v0.w, m0.w);
    union { short s[4]; uint2 u; } td, tm;
    td.s[0]=f2bf(d0.x); td.s[1]=f2bf(d0.y); td.s[2]=f2bf(d0.z); td.s[3]=f2bf(d0.w);
    tm.s[0]=f2bf(m0.x); tm.s[1]=f2bf(m0.y); tm.s[2]=f2bf(m0.z); tm.s[3]=f2bf(m0.w);
    *(uint2*)&dbuf[sfo] = td.u;
    *(uint2*)&xbuf[sfo] = tm.u;
    pv4 = *(const float4*)&values[sbase + Dn];
    pm4 = *(const float4*)&masks[sbase + Dn];
    pd4 = *(const float4*)&deltas[sbase + Dn];
  }
  float hreg[4] = {0.f, 0.f, 0.f, 0.f};
  float lacc[4] = {0.f, 0.f, 0.f, 0.f};
  float vxq[4] = {0.f, 0.f, 0.f, 0.f};
  float il = 0.f;
  __syncthreads();

  const int wb = w * 6 * 512;   // whh_l wave base
  const int cb = w * 3 * 512;   // comb_l wave base

  #pragma unroll 1
  for (int t = 0; t < Tn; ++t) {
    const float srm = rmsum[t];

    // ---- P1: gh + gi-kt0 (all) | vx + gamma + vc1 + il_x (waves 0-2) ----
    f32x4 A0 = {0,0,0,0}, A1 = {0,0,0,0}, A2 = {0,0,0,0}, A3 = {0,0,0,0};
    s8 ah0 = *(const s8*)&hbuf[lw8];
    s8 ah1 = *(const s8*)&hbuf[512 + lw8];
    A0 = __builtin_amdgcn_mfma_f32_16x16x32_bf16(ah0, *(const s8*)&whh_l[wb + lw8], A0, 0, 0, 0);
    A0 = __builtin_amdgcn_mfma_f32_16x16x32_bf16(ah1, *(const s8*)&whh_l[wb + 512 + lw8], A0, 0, 0, 0);
    A1 = __builtin_amdgcn_mfma_f32_16x16x32_bf16(ah0, *(const s8*)&whh_l[wb + 1024 + lw8], A1, 0, 0, 0);
    A1 = __builtin_amdgcn_mfma_f32_16x16x32_bf16(ah1, *(const s8*)&whh_l[wb + 1536 + lw8], A1, 0, 0, 0);
    A3 = __builtin_amdgcn_mfma_f32_16x16x32_bf16(ah0, *(const s8*)&whh_l[wb + 2048 + lw8], A3, 0, 0, 0);
    A3 = __builtin_amdgcn_mfma_f32_16x16x32_bf16(ah1, *(const s8*)&whh_l[wb + 2560 + lw8], A3, 0, 0, 0);
    {
      s8 ax0 = *(const s8*)&xbuf[lw8];
      A0 = __builtin_amdgcn_mfma_f32_16x16x32_bf16(ax0, wih[0], A0, 0, 0, 0);
      A1 = __builtin_amdgcn_mfma_f32_16x16x32_bf16(ax0, wih[4], A1, 0, 0, 0);
      A2 = __builtin_amdgcn_mfma_f32_16x16x32_bf16(ax0, wih[8], A2, 0, 0, 0);
    }
    if (sw) {
      f32x4 X = {0,0,0,0}, Gm = {0,0,0,0};
      X = __builtin_amdgcn_mfma_f32_16x16x32_bf16(ah0, *(const s8*)&hist_l[lw8], X, 0, 0, 0);
      X = __builtin_amdgcn_mfma_f32_16x16x32_bf16(ah1, *(const s8*)&hist_l[512 + lw8], X, 0, 0, 0);
      s8 ad0 = *(const s8*)&dbuf[lw8];
      s8 ad1 = *(const s8*)&dbuf[512 + lw8];
      Gm = __builtin_amdgcn_mfma_f32_16x16x32_bf16(ad0, dec2[0], Gm, 0, 0, 0);
      Gm = __builtin_amdgcn_mfma_f32_16x16x32_bf16(ad1, dec2[1], Gm, 0, 0, 0);
      #pragma unroll
      for (int q = 0; q < 4; ++q) vxq[q] = X[q] + histb;
      if (nsm < Dn) {
        #pragma unroll
        for (int q = 0; q < 4; ++q) {
          int rr = r4 * 4 + q;
          float g = __expf(-fmaxf(Gm[q] + db, 0.f));
          xbuf[gb + rr * 8] = f2bf(g);
          float2 vm = vm_s[rr * VMST + nsm];
          il += srm * fabsf(vxq[q] - vm.x) * vm.y;
          vcbuf[vb1 + rr * 8] = f2bf(vm.y * vm.x + (1.f - vm.y) * vxq[q]);
        }
      }
    }
    __syncthreads();  // b1: gamma + vc1 ready

    // ---- P2: gi-kt1 (all) | feat + comb + impute chain + vc2 (waves 0-2) ----
    s8 ax1 = *(const s8*)&xbuf[512 + lw8];
    A0 = __builtin_amdgcn_mfma_f32_16x16x32_bf16(ax1, wih[1], A0, 0, 0, 0);
    A1 = __builtin_amdgcn_mfma_f32_16x16x32_bf16(ax1, wih[5], A1, 0, 0, 0);
    A2 = __builtin_amdgcn_mfma_f32_16x16x32_bf16(ax1, wih[9], A2, 0, 0, 0);
    if (sw) {
      f32x4 Z = {0,0,0,0}, Bc = {0,0,0,0};
      s8 av0 = *(const s8*)&vcbuf[lw8];
      s8 av1 = *(const s8*)&vcbuf[512 + lw8];
      Z = __builtin_amdgcn_mfma_f32_16x16x32_bf16(av0, feat2[0], Z, 0, 0, 0);
      Z = __builtin_amdgcn_mfma_f32_16x16x32_bf16(av1, feat2[1], Z, 0, 0, 0);
      s8 cx0 = *(const s8*)&xbuf[lw8];
      s8 cx2 = *(const s8*)&xbuf[1024 + lw8];  // stale vc2 slots x zero weight: benign
      Bc = __builtin_amdgcn_mfma_f32_16x16x32_bf16(cx0, *(const s8*)&comb_l[cb + lw8], Bc, 0, 0, 0);
      Bc = __builtin_amdgcn_mfma_f32_16x16x32_bf16(ax1, *(const s8*)&comb_l[cb + 512 + lw8], Bc, 0, 0, 0);
      Bc = __builtin_amdgcn_mfma_f32_16x16x32_bf16(cx2, *(const s8*)&comb_l[cb + 1024 + lw8], Bc, 0, 0, 0);
      if (nsm < Dn) {
        #pragma unroll
        for (int q = 0; q < 4; ++q) {
          int rr = r4 * 4 + q;
          float beta = sigf(Bc[q] + cbv);
          float vz = Z[q] + fb;
          float2 vm = vm_s[rr * VMST + nsm];
          il += srm * fabsf(vz - vm.x) * vm.y;
          float vh = vz * beta + vxq[q] * (1.f - beta);
          il += srm * fabsf(vh - vm.x) * vm.y;
          float vc2 = vm.y * vm.x + (1.f - vm.y) * vh;
          if (rr < ROWS) out[1 + ((size_t)(row0 + rr) * Tn + t) * Dn + nsm] = vc2;
          xbuf[vb + rr * 8] = f2bf(vc2);
        }
      }
    }
    __syncthreads();  // b2: vc2 ready

    // ---- P3: gi-kt2/3 + GRU (all) | stage t+1, prefetch t+2 (lanes<18) ----
    {
      s8 ax2 = *(const s8*)&xbuf[1024 + lw8];
      s8 ax3 = *(const s8*)&xbuf[1536 + lw8];
      A0 = __builtin_amdgcn_mfma_f32_16x16x32_bf16(ax2, wih[2], A0, 0, 0, 0);
      A1 = __builtin_amdgcn_mfma_f32_16x16x32_bf16(ax2, wih[6], A1, 0, 0, 0);
      A2 = __builtin_amdgcn_mfma_f32_16x16x32_bf16(ax2, wih[10], A2, 0, 0, 0);
      A0 = __builtin_amdgcn_mfma_f32_16x16x32_bf16(ax3, wih[3], A0, 0, 0, 0);
      A1 = __builtin_amdgcn_mfma_f32_16x16x32_bf16(ax3, wih[7], A1, 0, 0, 0);
      A2 = __builtin_amdgcn_mfma_f32_16x16x32_bf16(ax3, wih[11], A2, 0, 0, 0);
    }
    #pragma unroll
    for (int q = 0; q < 4; ++q) {
      float rg = sigf(A0[q] + br);
      float zg = sigf(A1[q] + bz);
      float ng = tanhfast(A2[q] + bin_ + rg * (A3[q] + bhn));
      float hn = (1.f - zg) * ng + zg * hreg[q];
      hreg[q] = hn;
      lacc[q] += hn * ow;
      hbuf[hb + (r4 * 4 + q) * 8] = f2bf(hn);
    }
    if (stg) {
      if (t + 1 < Tn) {
        *(float4*)&vm_s[svo]     = make_float4(pv4.x, pm4.x, pv4.y, pm4.y);
        *(float4*)&vm_s[svo + 2] = make_float4(pv4.z, pm4.z, pv4.w, pm4.w);
        union { short s[4]; uint2 u; } td, tm;
        td.s[0]=f2bf(pd4.x); td.s[1]=f2bf(pd4.y); td.s[2]=f2bf(pd4.z); td.s[3]=f2bf(pd4.w);
        tm.s[0]=f2bf(pm4.x); tm.s[1]=f2bf(pm4.y); tm.s[2]=f2bf(pm4.z); tm.s[3]=f2bf(pm4.w);
        *(uint2*)&dbuf[sfo] = td.u;
        *(uint2*)&xbuf[sfo] = tm.u;
      }
      if (t + 2 < Tn) {
        size_t o = sbase + (size_t)(t + 2) * Dn;
        pv4 = *(const float4*)&values[o];
        pm4 = *(const float4*)&masks[o];
        pd4 = *(const float4*)&deltas[o];
      }
    }
    __syncthreads();  // b3: end of step
  }

  // ---- epilogue: reduce il, logits, pred, class loss ----
  red_s[tid] = il;
  __syncthreads();
  for (int k = 128; k > 0; k >>= 1) {
    if (tid < k) red_s[tid] += red_s[tid + k];
    __syncthreads();
  }
  if (tid == 0) atomicAdd(&ws_acc[0], red_s[0]);
  if (tid < 16) red16[tid] = 0.f;
  __syncthreads();
  if (r4 < 2) {   // rows 0..7 only
    #pragma unroll
    for (int q = 0; q < 4; ++q) atomicAdd(&red16[r4 * 4 + q], lacc[q]);
  }
  __syncthreads();

  if (tid < ROWS) {
    float lg = red16[tid] / (float)Tn + out_b[0];
    int rg = row0 + tid;
    float pred = sigf(lg);
    out[1 + (size_t)Bsz * Tn * Dn + rg] = pred;
    float y = label[rg], wt = is_train[rg];
    float bce = fmaxf(lg, 0.f) - lg * y + log1pf(__expf(-fabsf(lg)));
    atomicAdd(&ws_acc[1], bce * wt);
    atomicAdd(&ws_acc[2], wt);
  }
}

// ---------------- finalize loss -------------------------------------------------
__global__ void fin_k(const float* __restrict__ ws, float* __restrict__ out) {
  out[0] = ws[1] / (ws[2] + EPSf) + ws[0] / (float)Tn;
}

extern "C" void kernel_launch(void* const* d_in, const int* in_sizes, int n_in,
                              void* d_out, int out_size, void* d_ws, size_t ws_size,
                              hipStream_t stream) {
  const float* values   = (const float*)d_in[0];
  const float* masks    = (const float*)d_in[1];
  const float* deltas   = (const float*)d_in[2];
  const float* label    = (const float*)d_in[3];
  const float* is_train = (const float*)d_in[4];
  const float* W_ih     = (const float*)d_in[5];
  const float* W_hh     = (const float*)d_in[6];
  const float* b_ih     = (const float*)d_in[7];
  const float* b_hh     = (const float*)d_in[8];
  const float* hist_W   = (const float*)d_in[9];
  const float* hist_b   = (const float*)d_in[10];
  const float* feat_W   = (const float*)d_in[11];
  const float* feat_b   = (const float*)d_in[12];
  const float* decay_W  = (const float*)d_in[13];
  const float* decay_b  = (const float*)d_in[14];
  const float* comb_W   = (const float*)d_in[15];
  const float* comb_b   = (const float*)d_in[16];
  const float* out_W    = (const float*)d_in[17];
  const float* out_b    = (const float*)d_in[18];

  float* ws = (float*)d_ws;
  float* rmsum = ws + 4;
  float* out = (float*)d_out;

  hipMemsetAsync(d_ws, 0, 16, stream);
  msum_k<<<Tn, 256, 0, stream>>>((const float4*)masks, rmsum);
  brits_main<<<Bsz / ROWS, 256, 0, stream>>>(
      values, masks, deltas, label, is_train, W_ih, W_hh, b_ih, b_hh,
      hist_W, hist_b, feat_W, feat_b, decay_W, decay_b, comb_W, comb_b,
      out_W, out_b, out, rmsum, ws);
  fin_k<<<1, 1, 0, stream>>>(ws, out);
}

// Round 7
// 697.976 us; speedup vs baseline: 4.0471x; 1.0106x over previous
//
#include <hip/hip_runtime.h>
#include <hip/hip_bf16.h>

// BRITS-style RNN (B=4096, T=256, D=36, H=64) on gfx950.
// R7: 256 blocks x 960 threads (15 waves), ROWS=16 (all rows real), 3 barriers.
// Fine role split so each SIMD carries ~4 active waves and no wave's phase chain
// exceeds ~5 MFMA + one epilogue:
//   waves 0-3 "r", 4-7 "z": gh(2)+gi-kt0 in P1; gi-kt1 in P2 then ds_write_b128
//     partial acc to LDS; P3: staging (t+1 LDS writes, t+2 float4 prefetch).
//   waves 8-11 "n": gh_n (separate acc) + gi-kt0/kt1; P3: kt2/kt3 for n AND for
//     r,z using LDS partials as MFMA C-in (same lane mapping), GRU update, hbuf.
//   waves 12-14 "S": vx (hist replicated over all 16 B-cols -> vx in regs),
//     gamma, vc1 (P1); feat+comb+impute chain+vc2 (P2).
// Frag-linear LDS layout -> conflict-free ds_read_b128 on all MFMA operands.

#define Bsz 4096
#define Tn  256
#define Dn  36
#define ROWS 16
#define EPSf 1e-5f
#define VMST 38

using f32x4 = __attribute__((ext_vector_type(4))) float;
using s8    = __attribute__((ext_vector_type(8))) short;

__device__ __forceinline__ short f2bf(float x) {
  return (short)__bfloat16_as_ushort(__float2bfloat16(x));
}
__device__ __forceinline__ float sigf(float x) { return 1.f / (1.f + __expf(-x)); }
__device__ __forceinline__ float tanhfast(float x) { return 1.f - 2.f / (1.f + __expf(2.f * x)); }
// fragment-linear offset for element (row, k) of an MFMA A-tile (16 rows, bf16):
// lane = ((k%32)/8)*16 + row, addr = (k/32)*512 + lane*8 + k%8  (shorts)
__device__ __forceinline__ int fragoff(int row, int k) {
  return ((k >> 5) << 9) + (((k >> 3) & 3) << 7) + (row << 3) + (k & 7);
}

// ---------------- prepass: rmsum[t] = 1/(sum(masks[:,t,:]) + EPS) -------------
__global__ void msum_k(const float4* __restrict__ masks4, float* __restrict__ rmsum) {
  int t = blockIdx.x;
  float s = 0.f;
  for (int r = threadIdx.x; r < Bsz; r += 256) {
    const float4* mp = masks4 + ((size_t)r * Tn + t) * 9;
    #pragma unroll
    for (int j = 0; j < 9; ++j) { float4 v = mp[j]; s += v.x + v.y + v.z + v.w; }
  }
  __shared__ float red[256];
  red[threadIdx.x] = s;
  __syncthreads();
  for (int k = 128; k > 0; k >>= 1) {
    if (threadIdx.x < k) red[threadIdx.x] += red[threadIdx.x + k];
    __syncthreads();
  }
  if (threadIdx.x == 0) rmsum[t] = 1.f / (red[0] + EPSf);
}

// ---------------- main ---------------------------------------------------------
__global__ __launch_bounds__(960, 1) void brits_main(
    const float* __restrict__ values, const float* __restrict__ masks,
    const float* __restrict__ deltas, const float* __restrict__ label,
    const float* __restrict__ is_train,
    const float* __restrict__ W_ih, const float* __restrict__ W_hh,
    const float* __restrict__ b_ih, const float* __restrict__ b_hh,
    const float* __restrict__ hist_W, const float* __restrict__ hist_b,
    const float* __restrict__ feat_W, const float* __restrict__ feat_b,
    const float* __restrict__ decay_W, const float* __restrict__ decay_b,
    const float* __restrict__ comb_W, const float* __restrict__ comb_b,
    const float* __restrict__ out_W, const float* __restrict__ out_b,
    float* __restrict__ out, const float* __restrict__ rmsum,
    float* __restrict__ ws_acc /* [0] il, [1] cls, [2] wsum */) {

  __shared__ __align__(16) float2 vm_s[ROWS * VMST];   // (value, mask) f32
  __shared__ float  red_s[1024];
  __shared__ float  red16[16];
  __shared__ __align__(16) float pacc_l[8][64][4];     // r,z partial accs, 8KB
  __shared__ __align__(16) short dbuf[1024];   // delta K=64 frag-linear ([36,64)=0)
  __shared__ __align__(16) short vcbuf[1024];  // vc1 K=64 frag-linear
  __shared__ __align__(16) short hbuf[1024];   // h bf16 K=64 frag-linear
  __shared__ __align__(16) short xbuf[2048];   // [mask(0:36)|gamma(36:72)|vc2(72:108)|0]

  const int tid  = threadIdx.x;
  const int w    = tid >> 6;        // wave 0..14
  const int lane = tid & 63;
  const int lc   = lane & 15;
  const int r4   = lane >> 4;
  const int row0 = blockIdx.x * ROWS;
  const int k0b  = r4 * 8;
  const int lw8  = lane * 8;

  const bool isRZ = (w < 8);
  const bool isN  = (w >= 8 && w < 12);
  const bool isS  = (w >= 12);
  const int  dt   = isRZ ? (w & 3) : (w - 8);   // dim-tile for gate waves
  const int  dim  = 16 * (isS ? 0 : dt) + lc;   // gate dim (gate waves)
  const int  nsm  = 16 * (w - 12) + lc;         // S col (waves 12-14)
  const bool act  = isS && (nsm < Dn);

  // ---- weight fragments (<=10 per wave, role-overlaid) ----
  // r/z: [0]=wih kt0, [1]=wih kt1, [2..3]=whh kt0/1
  // n:   [0..3]=wih_n kt0-3, [4..5]=whh_n, [6..7]=wih_r kt2/3, [8..9]=wih_z kt2/3
  // S:   [0..1]=dec, [2..3]=feat(zero diag), [4..6]=comb, [7..8]=hist(all cols)
  s8 bfrag[10];
  #pragma unroll
  for (int i = 0; i < 10; ++i) bfrag[i] = (s8)(short)0;

  // W_ih column remap to xbuf k-space: xbuf=[mask|gamma|vc2], W_ih=[vc|mask|gamma]
  auto wih_elem = [&](int n, int xk) -> float {
    if (xk < 72) return W_ih[n * 108 + 36 + xk];
    if (xk < 108) return W_ih[n * 108 + xk - 72];
    return 0.f;
  };

  if (isRZ) {
    const int g = w >> 2;                  // 0=r, 1=z
    const int n = 64 * g + 16 * dt + lc;
    #pragma unroll
    for (int kt = 0; kt < 2; ++kt) {
      s8 fi, fh;
      #pragma unroll
      for (int e = 0; e < 8; ++e) {
        fi[e] = f2bf(wih_elem(n, k0b + 32 * kt + e));
        fh[e] = f2bf(W_hh[n * 64 + k0b + 32 * kt + e]);
      }
      bfrag[kt] = fi; bfrag[2 + kt] = fh;
    }
  } else if (isN) {
    const int n = 128 + 16 * dt + lc;
    #pragma unroll
    for (int kt = 0; kt < 4; ++kt) {
      s8 f;
      #pragma unroll
      for (int e = 0; e < 8; ++e) f[e] = f2bf(wih_elem(n, k0b + 32 * kt + e));
      bfrag[kt] = f;
    }
    #pragma unroll
    for (int kt = 0; kt < 2; ++kt) {
      s8 fh, fr, fz;
      #pragma unroll
      for (int e = 0; e < 8; ++e) {
        fh[e] = f2bf(W_hh[n * 64 + k0b + 32 * kt + e]);
        fr[e] = f2bf(wih_elem(16 * dt + lc,      k0b + 32 * (2 + kt) + e));
        fz[e] = f2bf(wih_elem(64 + 16 * dt + lc, k0b + 32 * (2 + kt) + e));
      }
      bfrag[4 + kt] = fh; bfrag[6 + kt] = fr; bfrag[8 + kt] = fz;
    }
  } else {
    #pragma unroll
    for (int kt = 0; kt < 2; ++kt) {
      s8 fd, ff, fh;
      #pragma unroll
      for (int e = 0; e < 8; ++e) {
        int k = k0b + 32 * kt + e;
        fd[e] = f2bf((act && k < Dn) ? decay_W[nsm * Dn + k] : 0.f);
        ff[e] = f2bf((act && k < Dn && k != nsm) ? feat_W[nsm * Dn + k] : 0.f);
        fh[e] = f2bf(hist_W[k]);   // replicated across ALL 16 B-cols
      }
      bfrag[kt] = fd; bfrag[2 + kt] = ff; bfrag[7 + kt] = fh;
    }
    #pragma unroll
    for (int kt = 0; kt < 3; ++kt) {
      s8 f;
      #pragma unroll
      for (int e = 0; e < 8; ++e) {
        int xk = k0b + 32 * kt + e;
        // comb input [gamma(0:36)|mask(36:72)]; xbuf k-space [mask|gamma|...]
        float wv = 0.f;
        if (act) {
          if (xk < 36) wv = comb_W[nsm * 72 + 36 + xk];
          else if (xk < 72) wv = comb_W[nsm * 72 + xk - 36];
        }
        f[e] = f2bf(wv);
      }
      bfrag[4 + kt] = f;
    }
  }

  // per-lane constants
  const float db   = act ? decay_b[nsm] : 0.f;
  const float fb   = act ? feat_b[nsm] : 0.f;
  const float cbv  = act ? comb_b[nsm] : 0.f;
  const float br   = isN ? (b_ih[dim] + b_hh[dim]) : 0.f;
  const float bz   = isN ? (b_ih[64 + dim] + b_hh[64 + dim]) : 0.f;
  const float bin_ = isN ? b_ih[128 + dim] : 0.f;
  const float bhn  = isN ? b_hh[128 + dim] : 0.f;
  const float ow   = isN ? out_W[dim] : 0.f;
  const float histb = hist_b[0];

  // write offsets
  const int gb  = fragoff(0, 36 + (act ? nsm : 0));
  const int vb1 = fragoff(0, (act ? nsm : 0));
  const int vb  = fragoff(0, 72 + (act ? nsm : 0));
  const int hb  = fragoff(0, dim);

  // ---- staging geometry: 144 quad-slots (16 rows x 9 quads) on tids 0..143 ----
  const bool stg = (tid < 144);
  const int srow = tid / 9;
  const int squad = tid - srow * 9;
  const size_t sbase = ((size_t)(row0 + srow) * Tn) * Dn + squad * 4;
  const int sfo = fragoff(srow, squad * 4);  // contiguous 4-short frag slot
  const int svo = srow * VMST + squad * 4;   // vm_s float2 index (even)

  // ---- init LDS ----
  for (int i = tid; i < 1024; i += 960) { dbuf[i] = 0; vcbuf[i] = 0; hbuf[i] = 0; }
  for (int i = tid; i < 2048; i += 960) xbuf[i] = 0;
  __syncthreads();

  // ---- prologue: stage t=0, prefetch t=1 ----
  float4 pv4 = {0,0,0,0}, pm4 = {0,0,0,0}, pd4 = {0,0,0,0};
  if (stg) {
    float4 v0 = *(const float4*)&values[sbase];
    float4 m0 = *(const float4*)&masks[sbase];
    float4 d0 = *(const float4*)&deltas[sbase];
    *(float4*)&vm_s[svo]     = make_float4(v0.x, m0.x, v0.y, m0.y);
    *(float4*)&vm_s[svo + 2] = make_float4(v0.z, m0.z, v0.w, m0.w);
    union { short s[4]; uint2 u; } td, tm;
    td.s[0]=f2bf(d0.x); td.s[1]=f2bf(d0.y); td.s[2]=f2bf(d0.z); td.s[3]=f2bf(d0.w);
    tm.s[0]=f2bf(m0.x); tm.s[1]=f2bf(m0.y); tm.s[2]=f2bf(m0.z); tm.s[3]=f2bf(m0.w);
    *(uint2*)&dbuf[sfo] = td.u;
    *(uint2*)&xbuf[sfo] = tm.u;
    pv4 = *(const float4*)&values[sbase + Dn];
    pm4 = *(const float4*)&masks[sbase + Dn];
    pd4 = *(const float4*)&deltas[sbase + Dn];
  }
  float hreg[4] = {0.f, 0.f, 0.f, 0.f};
  float lacc[4] = {0.f, 0.f, 0.f, 0.f};
  float vxq[4] = {0.f, 0.f, 0.f, 0.f};
  float il = 0.f;
  f32x4 Ag = {0,0,0,0};            // r/z partial
  f32x4 A2 = {0,0,0,0}, A3 = {0,0,0,0};  // n: gi acc, gh acc
  __syncthreads();

  #pragma unroll 1
  for (int t = 0; t < Tn; ++t) {
    const float srm = rmsum[t];

    // ---- P1 ----
    if (!isS) {
      s8 ah0 = *(const s8*)&hbuf[lw8];
      s8 ah1 = *(const s8*)&hbuf[512 + lw8];
      s8 ax0 = *(const s8*)&xbuf[lw8];
      if (isRZ) {
        Ag = (f32x4){0,0,0,0};
        Ag = __builtin_amdgcn_mfma_f32_16x16x32_bf16(ah0, bfrag[2], Ag, 0, 0, 0);
        Ag = __builtin_amdgcn_mfma_f32_16x16x32_bf16(ah1, bfrag[3], Ag, 0, 0, 0);
        Ag = __builtin_amdgcn_mfma_f32_16x16x32_bf16(ax0, bfrag[0], Ag, 0, 0, 0);
      } else {
        A2 = (f32x4){0,0,0,0}; A3 = (f32x4){0,0,0,0};
        A3 = __builtin_amdgcn_mfma_f32_16x16x32_bf16(ah0, bfrag[4], A3, 0, 0, 0);
        A3 = __builtin_amdgcn_mfma_f32_16x16x32_bf16(ah1, bfrag[5], A3, 0, 0, 0);
        A2 = __builtin_amdgcn_mfma_f32_16x16x32_bf16(ax0, bfrag[0], A2, 0, 0, 0);
      }
    } else {
      s8 ah0 = *(const s8*)&hbuf[lw8];
      s8 ah1 = *(const s8*)&hbuf[512 + lw8];
      s8 ad0 = *(const s8*)&dbuf[lw8];
      s8 ad1 = *(const s8*)&dbuf[512 + lw8];
      f32x4 X = {0,0,0,0}, Gm = {0,0,0,0};
      X  = __builtin_amdgcn_mfma_f32_16x16x32_bf16(ah0, bfrag[7], X, 0, 0, 0);
      X  = __builtin_amdgcn_mfma_f32_16x16x32_bf16(ah1, bfrag[8], X, 0, 0, 0);
      Gm = __builtin_amdgcn_mfma_f32_16x16x32_bf16(ad0, bfrag[0], Gm, 0, 0, 0);
      Gm = __builtin_amdgcn_mfma_f32_16x16x32_bf16(ad1, bfrag[1], Gm, 0, 0, 0);
      #pragma unroll
      for (int q = 0; q < 4; ++q) vxq[q] = X[q] + histb;
      if (act) {
        #pragma unroll
        for (int q = 0; q < 4; ++q) {
          int rr = r4 * 4 + q;
          float g = __expf(-fmaxf(Gm[q] + db, 0.f));
          xbuf[gb + rr * 8] = f2bf(g);
          float2 vm = vm_s[rr * VMST + nsm];
          il += srm * fabsf(vxq[q] - vm.x) * vm.y;
          vcbuf[vb1 + rr * 8] = f2bf(vm.y * vm.x + (1.f - vm.y) * vxq[q]);
        }
      }
    }
    __syncthreads();  // b1: gamma + vc1 ready

    // ---- P2 ----
    if (isRZ) {
      s8 ax1 = *(const s8*)&xbuf[512 + lw8];
      Ag = __builtin_amdgcn_mfma_f32_16x16x32_bf16(ax1, bfrag[1], Ag, 0, 0, 0);
      *(f32x4*)&pacc_l[w][lane][0] = Ag;
    } else if (isN) {
      s8 ax1 = *(const s8*)&xbuf[512 + lw8];
      A2 = __builtin_amdgcn_mfma_f32_16x16x32_bf16(ax1, bfrag[1], A2, 0, 0, 0);
    } else {
      f32x4 Z = {0,0,0,0}, Bc = {0,0,0,0};
      s8 av0 = *(const s8*)&vcbuf[lw8];
      s8 av1 = *(const s8*)&vcbuf[512 + lw8];
      Z = __builtin_amdgcn_mfma_f32_16x16x32_bf16(av0, bfrag[2], Z, 0, 0, 0);
      Z = __builtin_amdgcn_mfma_f32_16x16x32_bf16(av1, bfrag[3], Z, 0, 0, 0);
      s8 cx0 = *(const s8*)&xbuf[lw8];
      s8 cx1 = *(const s8*)&xbuf[512 + lw8];
      s8 cx2 = *(const s8*)&xbuf[1024 + lw8];  // stale vc2 x zero weight: benign
      Bc = __builtin_amdgcn_mfma_f32_16x16x32_bf16(cx0, bfrag[4], Bc, 0, 0, 0);
      Bc = __builtin_amdgcn_mfma_f32_16x16x32_bf16(cx1, bfrag[5], Bc, 0, 0, 0);
      Bc = __builtin_amdgcn_mfma_f32_16x16x32_bf16(cx2, bfrag[6], Bc, 0, 0, 0);
      if (act) {
        #pragma unroll
        for (int q = 0; q < 4; ++q) {
          int rr = r4 * 4 + q;
          float beta = sigf(Bc[q] + cbv);
          float vz = Z[q] + fb;
          float2 vm = vm_s[rr * VMST + nsm];
          il += srm * fabsf(vz - vm.x) * vm.y;
          float vh = vz * beta + vxq[q] * (1.f - beta);
          il += srm * fabsf(vh - vm.x) * vm.y;
          float vc2 = vm.y * vm.x + (1.f - vm.y) * vh;
          out[1 + ((size_t)(row0 + rr) * Tn + t) * Dn + nsm] = vc2;
          xbuf[vb + rr * 8] = f2bf(vc2);
        }
      }
    }
    __syncthreads();  // b2: vc2 + r,z partials ready

    // ---- P3 ----
    if (isN) {
      s8 ax2 = *(const s8*)&xbuf[1024 + lw8];
      s8 ax3 = *(const s8*)&xbuf[1536 + lw8];
      A2 = __builtin_amdgcn_mfma_f32_16x16x32_bf16(ax2, bfrag[2], A2, 0, 0, 0);
      A2 = __builtin_amdgcn_mfma_f32_16x16x32_bf16(ax3, bfrag[3], A2, 0, 0, 0);
      f32x4 Ar = *(const f32x4*)&pacc_l[dt][lane][0];
      f32x4 Az = *(const f32x4*)&pacc_l[4 + dt][lane][0];
      Ar = __builtin_amdgcn_mfma_f32_16x16x32_bf16(ax2, bfrag[6], Ar, 0, 0, 0);
      Ar = __builtin_amdgcn_mfma_f32_16x16x32_bf16(ax3, bfrag[7], Ar, 0, 0, 0);
      Az = __builtin_amdgcn_mfma_f32_16x16x32_bf16(ax2, bfrag[8], Az, 0, 0, 0);
      Az = __builtin_amdgcn_mfma_f32_16x16x32_bf16(ax3, bfrag[9], Az, 0, 0, 0);
      #pragma unroll
      for (int q = 0; q < 4; ++q) {
        float rg = sigf(Ar[q] + br);
        float zg = sigf(Az[q] + bz);
        float ng = tanhfast(A2[q] + bin_ + rg * (A3[q] + bhn));
        float hn = (1.f - zg) * ng + zg * hreg[q];
        hreg[q] = hn;
        lacc[q] += hn * ow;
        hbuf[hb + (r4 * 4 + q) * 8] = f2bf(hn);
      }
    } else if (stg) {
      if (t + 1 < Tn) {
        *(float4*)&vm_s[svo]     = make_float4(pv4.x, pm4.x, pv4.y, pm4.y);
        *(float4*)&vm_s[svo + 2] = make_float4(pv4.z, pm4.z, pv4.w, pm4.w);
        union { short s[4]; uint2 u; } td, tm;
        td.s[0]=f2bf(pd4.x); td.s[1]=f2bf(pd4.y); td.s[2]=f2bf(pd4.z); td.s[3]=f2bf(pd4.w);
        tm.s[0]=f2bf(pm4.x); tm.s[1]=f2bf(pm4.y); tm.s[2]=f2bf(pm4.z); tm.s[3]=f2bf(pm4.w);
        *(uint2*)&dbuf[sfo] = td.u;
        *(uint2*)&xbuf[sfo] = tm.u;
      }
      if (t + 2 < Tn) {
        size_t o = sbase + (size_t)(t + 2) * Dn;
        pv4 = *(const float4*)&values[o];
        pm4 = *(const float4*)&masks[o];
        pd4 = *(const float4*)&deltas[o];
      }
    }
    __syncthreads();  // b3: end of step (hbuf + staged t+1 ready)
  }

  // ---- epilogue: reduce il, logits, pred, class loss ----
  red_s[tid] = il;
  if (tid < 64) red_s[960 + tid] = 0.f;
  __syncthreads();
  for (int k = 512; k > 0; k >>= 1) {
    if (tid < k) red_s[tid] += red_s[tid + k];
    __syncthreads();
  }
  if (tid == 0) atomicAdd(&ws_acc[0], red_s[0]);
  if (tid < 16) red16[tid] = 0.f;
  __syncthreads();
  if (isN) {
    #pragma unroll
    for (int q = 0; q < 4; ++q) atomicAdd(&red16[r4 * 4 + q], lacc[q]);
  }
  __syncthreads();

  if (tid < ROWS) {
    float lg = red16[tid] / (float)Tn + out_b[0];
    int rg = row0 + tid;
    float pred = sigf(lg);
    out[1 + (size_t)Bsz * Tn * Dn + rg] = pred;
    float y = label[rg], wt = is_train[rg];
    float bce = fmaxf(lg, 0.f) - lg * y + log1pf(__expf(-fabsf(lg)));
    atomicAdd(&ws_acc[1], bce * wt);
    atomicAdd(&ws_acc[2], wt);
  }
}

// ---------------- finalize loss -------------------------------------------------
__global__ void fin_k(const float* __restrict__ ws, float* __restrict__ out) {
  out[0] = ws[1] / (ws[2] + EPSf) + ws[0] / (float)Tn;
}

extern "C" void kernel_launch(void* const* d_in, const int* in_sizes, int n_in,
                              void* d_out, int out_size, void* d_ws, size_t ws_size,
                              hipStream_t stream) {
  const float* values   = (const float*)d_in[0];
  const float* masks    = (const float*)d_in[1];
  const float* deltas   = (const float*)d_in[2];
  const float* label    = (const float*)d_in[3];
  const float* is_train = (const float*)d_in[4];
  const float* W_ih     = (const float*)d_in[5];
  const float* W_hh     = (const float*)d_in[6];
  const float* b_ih     = (const float*)d_in[7];
  const float* b_hh     = (const float*)d_in[8];
  const float* hist_W   = (const float*)d_in[9];
  const float* hist_b   = (const float*)d_in[10];
  const float* feat_W   = (const float*)d_in[11];
  const float* feat_b   = (const float*)d_in[12];
  const float* decay_W  = (const float*)d_in[13];
  const float* decay_b  = (const float*)d_in[14];
  const float* comb_W   = (const float*)d_in[15];
  const float* comb_b   = (const float*)d_in[16];
  const float* out_W    = (const float*)d_in[17];
  const float* out_b    = (const float*)d_in[18];

  float* ws = (float*)d_ws;
  float* rmsum = ws + 4;
  float* out = (float*)d_out;

  hipMemsetAsync(d_ws, 0, 16, stream);
  msum_k<<<Tn, 256, 0, stream>>>((const float4*)masks, rmsum);
  brits_main<<<Bsz / ROWS, 960, 0, stream>>>(
      values, masks, deltas, label, is_train, W_ih, W_hh, b_ih, b_hh,
      hist_W, hist_b, feat_W, feat_b, decay_W, decay_b, comb_W, comb_b,
      out_W, out_b, out, rmsum, ws);
  fin_k<<<1, 1, 0, stream>>>(ws, out);
}

// Round 8
// 447.648 us; speedup vs baseline: 6.3103x; 1.5592x over previous
//
#include <hip/hip_runtime.h>
#include <hip/hip_bf16.h>

// BRITS-style RNN (B=4096, T=256, D=36, H=64) on gfx950.
// R8: 2 barriers/step. Rows are independent through the whole imputation chain,
// so S-waves 4-7 each own a ROW SLICE {s,4+s,8+s,12+s} (acc slot q=s) and run the
// ENTIRE chain vx->gamma->vc1->feat->comb->impute->vc2 privately per step
// (wave-private vcbuf/cxbuf, lgkmcnt-only ordering, no barriers inside).
// G-waves 0-3 (gate dims 16w..16w+15, r/z/n): P1 gh+gi-kt0 + staging t+1;
// P2 gi-kt1..3 + GRU + hbuf. Cross-wave sync: barrier1 (gamma/vc2 -> gi),
// barrier2 (h -> next step). vm_s/dbuf/xbuf double-buffered by step parity.
// Single role-overlaid bf[23] fragment array; no launch_bounds minimum
// (R4/R7 showed forced caps -> 64 VGPR spill).

#define Bsz 4096
#define Tn  256
#define Dn  36
#define ROWS 16
#define EPSf 1e-5f
#define VMST 38

using f32x4 = __attribute__((ext_vector_type(4))) float;
using s8    = __attribute__((ext_vector_type(8))) short;

__device__ __forceinline__ short f2bf(float x) {
  return (short)__bfloat16_as_ushort(__float2bfloat16(x));
}
__device__ __forceinline__ float sigf(float x) { return 1.f / (1.f + __expf(-x)); }
__device__ __forceinline__ float tanhfast(float x) { return 1.f - 2.f / (1.f + __expf(2.f * x)); }
// fragment-linear offset for element (row, k) of an MFMA A-tile (16 rows, bf16):
// lane = ((k%32)/8)*16 + row, addr = (k/32)*512 + lane*8 + k%8  (shorts)
__device__ __forceinline__ int fragoff(int row, int k) {
  return ((k >> 5) << 9) + (((k >> 3) & 3) << 7) + (row << 3) + (k & 7);
}
// v[s] for wave-uniform runtime s without scratch (rule #20)
__device__ __forceinline__ float selq(f32x4 v, int s) {
  float a = (s & 1) ? v[1] : v[0];
  float b = (s & 1) ? v[3] : v[2];
  return (s & 2) ? b : a;
}

// ---------------- prepass: rmsum[t] = 1/(sum(masks[:,t,:]) + EPS) -------------
__global__ void msum_k(const float4* __restrict__ masks4, float* __restrict__ rmsum) {
  int t = blockIdx.x;
  float s = 0.f;
  for (int r = threadIdx.x; r < Bsz; r += 256) {
    const float4* mp = masks4 + ((size_t)r * Tn + t) * 9;
    #pragma unroll
    for (int j = 0; j < 9; ++j) { float4 v = mp[j]; s += v.x + v.y + v.z + v.w; }
  }
  __shared__ float red[256];
  red[threadIdx.x] = s;
  __syncthreads();
  for (int k = 128; k > 0; k >>= 1) {
    if (threadIdx.x < k) red[threadIdx.x] += red[threadIdx.x + k];
    __syncthreads();
  }
  if (threadIdx.x == 0) rmsum[t] = 1.f / (red[0] + EPSf);
}

// ---------------- main ---------------------------------------------------------
__global__ __launch_bounds__(512) void brits_main(
    const float* __restrict__ values, const float* __restrict__ masks,
    const float* __restrict__ deltas, const float* __restrict__ label,
    const float* __restrict__ is_train,
    const float* __restrict__ W_ih, const float* __restrict__ W_hh,
    const float* __restrict__ b_ih, const float* __restrict__ b_hh,
    const float* __restrict__ hist_W, const float* __restrict__ hist_b,
    const float* __restrict__ feat_W, const float* __restrict__ feat_b,
    const float* __restrict__ decay_W, const float* __restrict__ decay_b,
    const float* __restrict__ comb_W, const float* __restrict__ comb_b,
    const float* __restrict__ out_W, const float* __restrict__ out_b,
    float* __restrict__ out, const float* __restrict__ rmsum,
    float* __restrict__ ws_acc /* [0] il, [1] cls, [2] wsum */) {

  __shared__ __align__(16) float2 vm_s[2][ROWS * VMST];  // (value, mask), dbuf'd
  __shared__ float  red_s[512];
  __shared__ float  red16[16];
  __shared__ __align__(16) short hbuf[1024];        // h bf16, K=64 frag-linear
  __shared__ __align__(16) short dbuf[2][1024];     // delta, dbuf'd by parity
  __shared__ __align__(16) short xbuf[2][2048];     // [mask|gamma|vc2|pad] K=128
  __shared__ __align__(16) short vcbuf[4][1024];    // per-S-wave private vc1
  __shared__ __align__(16) short cxbuf[4][1536];    // per-S-wave [gamma|mask] K=96

  const int tid  = threadIdx.x;
  const int w    = tid >> 6;        // wave 0..7
  const int lane = tid & 63;
  const int lc   = lane & 15;
  const int r4   = lane >> 4;
  const int row0 = blockIdx.x * ROWS;
  const int k0b  = r4 * 8;
  const int lw8  = lane * 8;

  const bool isG = (w < 4);
  const int  sW  = isG ? 0 : (w - 4);       // S wave index 0..3
  const int  dim = 16 * (isG ? w : 0) + lc; // gate dim (G)
  const int  myrow = 4 * r4 + sW;           // S row owned at this lane (q = sW)

  // ---- role-overlaid weight fragments (single array -> shared regs) ----
  // G: [0..11] = wih (xbuf k-space remap), [12..17] = whh
  // S: [0..5]=dec, [6..11]=feat(zero diag), [12..20]=comb, [21..22]=hist(all cols)
  s8 bf[23];
  #pragma unroll
  for (int i = 0; i < 23; ++i) bf[i] = (s8)(short)0;

  if (isG) {
    #pragma unroll
    for (int g = 0; g < 3; ++g) {
      const int n = 64 * g + dim;
      #pragma unroll
      for (int kt = 0; kt < 4; ++kt) {
        s8 f;
        #pragma unroll
        for (int e = 0; e < 8; ++e) {
          int xk = k0b + 32 * kt + e;
          // xbuf k-space [mask(0:36)|gamma(36:72)|vc2(72:108)|pad]
          // W_ih cols    [vc(0:36)|mask(36:72)|gamma(72:108)]
          float wv = 0.f;
          if (xk < 72) wv = W_ih[n * 108 + 36 + xk];
          else if (xk < 108) wv = W_ih[n * 108 + xk - 72];
          f[e] = f2bf(wv);
        }
        bf[g * 4 + kt] = f;
      }
      #pragma unroll
      for (int kt = 0; kt < 2; ++kt) {
        s8 f;
        #pragma unroll
        for (int e = 0; e < 8; ++e) f[e] = f2bf(W_hh[n * 64 + k0b + 32 * kt + e]);
        bf[12 + g * 2 + kt] = f;
      }
    }
  } else {
    #pragma unroll
    for (int t3 = 0; t3 < 3; ++t3) {
      const int col = 16 * t3 + lc;
      const bool cok = (col < Dn);
      #pragma unroll
      for (int kt = 0; kt < 2; ++kt) {
        s8 fd, ff;
        #pragma unroll
        for (int e = 0; e < 8; ++e) {
          int k = k0b + 32 * kt + e;
          fd[e] = f2bf((cok && k < Dn) ? decay_W[col * Dn + k] : 0.f);
          ff[e] = f2bf((cok && k < Dn && k != col) ? feat_W[col * Dn + k] : 0.f);
        }
        bf[t3 * 2 + kt] = fd;
        bf[6 + t3 * 2 + kt] = ff;
      }
      #pragma unroll
      for (int kt = 0; kt < 3; ++kt) {
        s8 f;
        #pragma unroll
        for (int e = 0; e < 8; ++e) {
          int k = k0b + 32 * kt + e;   // cxbuf = [gamma(0:36)|mask(36:72)] = comb input order
          f[e] = f2bf((cok && k < 72) ? comb_W[col * 72 + k] : 0.f);
        }
        bf[12 + t3 * 3 + kt] = f;
      }
    }
    #pragma unroll
    for (int kt = 0; kt < 2; ++kt) {
      s8 f;
      #pragma unroll
      for (int e = 0; e < 8; ++e) f[e] = f2bf(hist_W[k0b + 32 * kt + e]); // all cols
      bf[21 + kt] = f;
    }
  }

  // per-lane constants
  float db3[3] = {0,0,0}, fb3[3] = {0,0,0}, cb3[3] = {0,0,0};
  float br = 0.f, bz = 0.f, bin_ = 0.f, bhn = 0.f, ow = 0.f;
  if (isG) {
    br   = b_ih[dim] + b_hh[dim];
    bz   = b_ih[64 + dim] + b_hh[64 + dim];
    bin_ = b_ih[128 + dim];
    bhn  = b_hh[128 + dim];
    ow   = out_W[dim];
  } else {
    #pragma unroll
    for (int t3 = 0; t3 < 3; ++t3) {
      int col = 16 * t3 + lc;
      if (col < Dn) { db3[t3] = decay_b[col]; fb3[t3] = feat_b[col]; cb3[t3] = comb_b[col]; }
    }
  }
  const float histb = hist_b[0];
  const int hb = fragoff(0, dim);

  // ---- staging geometry (G waves, tids 0..143): 16 rows x 9 quads ----
  const bool stg = (tid < 144);
  const int srow = tid / 9;
  const int squad = tid - srow * 9;
  const size_t sbase = ((size_t)(row0 + srow) * Tn) * Dn + squad * 4;
  const int sfo = fragoff(srow, squad * 4);
  const int svo = srow * VMST + squad * 4;

  // S P2 mask->cxbuf geometry (lane < 36)
  const int mrow = 4 * (lane / 9) + sW;
  const int mc0  = (lane % 9) * 4;

  // ---- init LDS ----
  for (int i = tid; i < 1024; i += 512) {
    hbuf[i] = 0; dbuf[0][i] = 0; dbuf[1][i] = 0;
    vcbuf[0][i] = 0; vcbuf[1][i] = 0; vcbuf[2][i] = 0; vcbuf[3][i] = 0;
  }
  for (int i = tid; i < 2048; i += 512) { xbuf[0][i] = 0; xbuf[1][i] = 0; }
  for (int i = tid; i < 1536; i += 512) {
    cxbuf[0][i] = 0; cxbuf[1][i] = 0; cxbuf[2][i] = 0; cxbuf[3][i] = 0;
  }
  __syncthreads();

  // ---- prologue: stage t=0 into parity 0; prefetch t=1 ----
  float4 pv = {0,0,0,0}, pm = {0,0,0,0}, pd = {0,0,0,0};
  if (stg) {
    float4 v0 = *(const float4*)&values[sbase];
    float4 m0 = *(const float4*)&masks[sbase];
    float4 d0 = *(const float4*)&deltas[sbase];
    *(float4*)&vm_s[0][svo]     = make_float4(v0.x, m0.x, v0.y, m0.y);
    *(float4*)&vm_s[0][svo + 2] = make_float4(v0.z, m0.z, v0.w, m0.w);
    union { short s[4]; uint2 u; } td, tm;
    td.s[0]=f2bf(d0.x); td.s[1]=f2bf(d0.y); td.s[2]=f2bf(d0.z); td.s[3]=f2bf(d0.w);
    tm.s[0]=f2bf(m0.x); tm.s[1]=f2bf(m0.y); tm.s[2]=f2bf(m0.z); tm.s[3]=f2bf(m0.w);
    *(uint2*)&dbuf[0][sfo] = td.u;
    *(uint2*)&xbuf[0][sfo] = tm.u;
    pv = *(const float4*)&values[sbase + Dn];
    pm = *(const float4*)&masks[sbase + Dn];
    pd = *(const float4*)&deltas[sbase + Dn];
  }
  __syncthreads();
  if (!isG && lane < 36) {   // cxbuf mask for t=0
    #pragma unroll
    for (int j = 0; j < 4; ++j)
      cxbuf[sW][fragoff(mrow, 36 + mc0 + j)] = f2bf(vm_s[0][mrow * VMST + mc0 + j].y);
  }

  float hreg[4] = {0.f, 0.f, 0.f, 0.f};
  float lacc[4] = {0.f, 0.f, 0.f, 0.f};
  float il = 0.f;
  __syncthreads();

  #pragma unroll 1
  for (int t = 0; t < Tn; ++t) {
    const float srm = rmsum[t];
    const int p = t & 1;
    f32x4 A0 = {0,0,0,0}, A1 = {0,0,0,0}, A2 = {0,0,0,0}, A3 = {0,0,0,0};

    // ================ P1 ================
    if (isG) {
      s8 ah0 = *(const s8*)&hbuf[lw8];
      s8 ah1 = *(const s8*)&hbuf[512 + lw8];
      s8 ax0 = *(const s8*)&xbuf[p][lw8];
      A0 = __builtin_amdgcn_mfma_f32_16x16x32_bf16(ah0, bf[12], A0, 0, 0, 0);
      A0 = __builtin_amdgcn_mfma_f32_16x16x32_bf16(ah1, bf[13], A0, 0, 0, 0);
      A1 = __builtin_amdgcn_mfma_f32_16x16x32_bf16(ah0, bf[14], A1, 0, 0, 0);
      A1 = __builtin_amdgcn_mfma_f32_16x16x32_bf16(ah1, bf[15], A1, 0, 0, 0);
      A3 = __builtin_amdgcn_mfma_f32_16x16x32_bf16(ah0, bf[16], A3, 0, 0, 0);
      A3 = __builtin_amdgcn_mfma_f32_16x16x32_bf16(ah1, bf[17], A3, 0, 0, 0);
      A0 = __builtin_amdgcn_mfma_f32_16x16x32_bf16(ax0, bf[0], A0, 0, 0, 0);
      A1 = __builtin_amdgcn_mfma_f32_16x16x32_bf16(ax0, bf[4], A1, 0, 0, 0);
      A2 = __builtin_amdgcn_mfma_f32_16x16x32_bf16(ax0, bf[8], A2, 0, 0, 0);
      // stage t+1 into parity p^1 (prefetched regs)
      if (stg && t + 1 < Tn) {
        *(float4*)&vm_s[p ^ 1][svo]     = make_float4(pv.x, pm.x, pv.y, pm.y);
        *(float4*)&vm_s[p ^ 1][svo + 2] = make_float4(pv.z, pm.z, pv.w, pm.w);
        union { short s[4]; uint2 u; } td, tm;
        td.s[0]=f2bf(pd.x); td.s[1]=f2bf(pd.y); td.s[2]=f2bf(pd.z); td.s[3]=f2bf(pd.w);
        tm.s[0]=f2bf(pm.x); tm.s[1]=f2bf(pm.y); tm.s[2]=f2bf(pm.z); tm.s[3]=f2bf(pm.w);
        *(uint2*)&dbuf[p ^ 1][sfo] = td.u;
        *(uint2*)&xbuf[p ^ 1][sfo] = tm.u;
      }
      if (stg && t + 2 < Tn) {
        size_t o = sbase + (size_t)(t + 2) * Dn;
        pv = *(const float4*)&values[o];
        pm = *(const float4*)&masks[o];
        pd = *(const float4*)&deltas[o];
      }
    } else {
      // ---- S: full per-row imputation chain, no barriers inside ----
      s8 ah0 = *(const s8*)&hbuf[lw8];
      s8 ah1 = *(const s8*)&hbuf[512 + lw8];
      s8 ad0 = *(const s8*)&dbuf[p][lw8];
      s8 ad1 = *(const s8*)&dbuf[p][512 + lw8];
      f32x4 X = {0,0,0,0};
      X = __builtin_amdgcn_mfma_f32_16x16x32_bf16(ah0, bf[21], X, 0, 0, 0);
      X = __builtin_amdgcn_mfma_f32_16x16x32_bf16(ah1, bf[22], X, 0, 0, 0);
      f32x4 Gm0 = {0,0,0,0}, Gm1 = {0,0,0,0}, Gm2 = {0,0,0,0};
      Gm0 = __builtin_amdgcn_mfma_f32_16x16x32_bf16(ad0, bf[0], Gm0, 0, 0, 0);
      Gm0 = __builtin_amdgcn_mfma_f32_16x16x32_bf16(ad1, bf[1], Gm0, 0, 0, 0);
      Gm1 = __builtin_amdgcn_mfma_f32_16x16x32_bf16(ad0, bf[2], Gm1, 0, 0, 0);
      Gm1 = __builtin_amdgcn_mfma_f32_16x16x32_bf16(ad1, bf[3], Gm1, 0, 0, 0);
      Gm2 = __builtin_amdgcn_mfma_f32_16x16x32_bf16(ad0, bf[4], Gm2, 0, 0, 0);
      Gm2 = __builtin_amdgcn_mfma_f32_16x16x32_bf16(ad1, bf[5], Gm2, 0, 0, 0);
      const float vx = selq(X, sW) + histb;

      float v3[3], m3[3];
      #pragma unroll
      for (int t3 = 0; t3 < 3; ++t3) {
        const int col = 16 * t3 + lc;
        float gmv = (t3 == 0) ? selq(Gm0, sW) : (t3 == 1) ? selq(Gm1, sW) : selq(Gm2, sW);
        v3[t3] = 0.f; m3[t3] = 0.f;
        if (col < Dn) {
          float g = __expf(-fmaxf(gmv + db3[t3], 0.f));
          short gbv = f2bf(g);
          xbuf[p][fragoff(myrow, 36 + col)] = gbv;   // for G's gi
          cxbuf[sW][fragoff(myrow, col)]    = gbv;   // for own comb
          float2 vm = vm_s[p][myrow * VMST + col];
          v3[t3] = vm.x; m3[t3] = vm.y;
          il += srm * fabsf(vx - vm.x) * vm.y;
          vcbuf[sW][fragoff(myrow, col)] = f2bf(vm.y * vm.x + (1.f - vm.y) * vx);
        }
      }
      // feat + comb (private buffers; compiler inserts lgkmcnt)
      s8 av0 = *(const s8*)&vcbuf[sW][lw8];
      s8 av1 = *(const s8*)&vcbuf[sW][512 + lw8];
      f32x4 Z0 = {0,0,0,0}, Z1 = {0,0,0,0}, Z2 = {0,0,0,0};
      Z0 = __builtin_amdgcn_mfma_f32_16x16x32_bf16(av0, bf[6],  Z0, 0, 0, 0);
      Z0 = __builtin_amdgcn_mfma_f32_16x16x32_bf16(av1, bf[7],  Z0, 0, 0, 0);
      Z1 = __builtin_amdgcn_mfma_f32_16x16x32_bf16(av0, bf[8],  Z1, 0, 0, 0);
      Z1 = __builtin_amdgcn_mfma_f32_16x16x32_bf16(av1, bf[9],  Z1, 0, 0, 0);
      Z2 = __builtin_amdgcn_mfma_f32_16x16x32_bf16(av0, bf[10], Z2, 0, 0, 0);
      Z2 = __builtin_amdgcn_mfma_f32_16x16x32_bf16(av1, bf[11], Z2, 0, 0, 0);
      s8 ac0 = *(const s8*)&cxbuf[sW][lw8];
      s8 ac1 = *(const s8*)&cxbuf[sW][512 + lw8];
      s8 ac2 = *(const s8*)&cxbuf[sW][1024 + lw8];
      f32x4 B0 = {0,0,0,0}, B1 = {0,0,0,0}, B2 = {0,0,0,0};
      B0 = __builtin_amdgcn_mfma_f32_16x16x32_bf16(ac0, bf[12], B0, 0, 0, 0);
      B0 = __builtin_amdgcn_mfma_f32_16x16x32_bf16(ac1, bf[13], B0, 0, 0, 0);
      B0 = __builtin_amdgcn_mfma_f32_16x16x32_bf16(ac2, bf[14], B0, 0, 0, 0);
      B1 = __builtin_amdgcn_mfma_f32_16x16x32_bf16(ac0, bf[15], B1, 0, 0, 0);
      B1 = __builtin_amdgcn_mfma_f32_16x16x32_bf16(ac1, bf[16], B1, 0, 0, 0);
      B1 = __builtin_amdgcn_mfma_f32_16x16x32_bf16(ac2, bf[17], B1, 0, 0, 0);
      B2 = __builtin_amdgcn_mfma_f32_16x16x32_bf16(ac0, bf[18], B2, 0, 0, 0);
      B2 = __builtin_amdgcn_mfma_f32_16x16x32_bf16(ac1, bf[19], B2, 0, 0, 0);
      B2 = __builtin_amdgcn_mfma_f32_16x16x32_bf16(ac2, bf[20], B2, 0, 0, 0);
      #pragma unroll
      for (int t3 = 0; t3 < 3; ++t3) {
        const int col = 16 * t3 + lc;
        if (col < Dn) {
          float zv = (t3 == 0) ? selq(Z0, sW) : (t3 == 1) ? selq(Z1, sW) : selq(Z2, sW);
          float bv = (t3 == 0) ? selq(B0, sW) : (t3 == 1) ? selq(B1, sW) : selq(B2, sW);
          float beta = sigf(bv + cb3[t3]);
          float vz = zv + fb3[t3];
          il += srm * fabsf(vz - v3[t3]) * m3[t3];
          float vh = vz * beta + vx * (1.f - beta);
          il += srm * fabsf(vh - v3[t3]) * m3[t3];
          float vc2 = m3[t3] * v3[t3] + (1.f - m3[t3]) * vh;
          out[1 + ((size_t)(row0 + myrow) * Tn + t) * Dn + col] = vc2;
          xbuf[p][fragoff(myrow, 72 + col)] = f2bf(vc2);
        }
      }
    }
    __syncthreads();  // b1: gamma + vc2 visible to G

    // ================ P2 ================
    if (isG) {
      s8 ax1 = *(const s8*)&xbuf[p][512 + lw8];
      s8 ax2 = *(const s8*)&xbuf[p][1024 + lw8];
      s8 ax3 = *(const s8*)&xbuf[p][1536 + lw8];
      A0 = __builtin_amdgcn_mfma_f32_16x16x32_bf16(ax1, bf[1], A0, 0, 0, 0);
      A1 = __builtin_amdgcn_mfma_f32_16x16x32_bf16(ax1, bf[5], A1, 0, 0, 0);
      A2 = __builtin_amdgcn_mfma_f32_16x16x32_bf16(ax1, bf[9], A2, 0, 0, 0);
      A0 = __builtin_amdgcn_mfma_f32_16x16x32_bf16(ax2, bf[2], A0, 0, 0, 0);
      A1 = __builtin_amdgcn_mfma_f32_16x16x32_bf16(ax2, bf[6], A1, 0, 0, 0);
      A2 = __builtin_amdgcn_mfma_f32_16x16x32_bf16(ax2, bf[10], A2, 0, 0, 0);
      A0 = __builtin_amdgcn_mfma_f32_16x16x32_bf16(ax3, bf[3], A0, 0, 0, 0);
      A1 = __builtin_amdgcn_mfma_f32_16x16x32_bf16(ax3, bf[7], A1, 0, 0, 0);
      A2 = __builtin_amdgcn_mfma_f32_16x16x32_bf16(ax3, bf[11], A2, 0, 0, 0);
      #pragma unroll
      for (int q = 0; q < 4; ++q) {
        float rg = sigf(A0[q] + br);
        float zg = sigf(A1[q] + bz);
        float ng = tanhfast(A2[q] + bin_ + rg * (A3[q] + bhn));
        float hn = (1.f - zg) * ng + zg * hreg[q];
        hreg[q] = hn;
        lacc[q] += hn * ow;
        hbuf[hb + (r4 * 4 + q) * 8] = f2bf(hn);
      }
    } else {
      if (t + 1 < Tn && lane < 36) {   // mask(t+1) -> private cxbuf
        #pragma unroll
        for (int j = 0; j < 4; ++j)
          cxbuf[sW][fragoff(mrow, 36 + mc0 + j)] =
              f2bf(vm_s[p ^ 1][mrow * VMST + mc0 + j].y);
      }
    }
    __syncthreads();  // b2: h(t) + staged t+1 visible
  }

  // ---- epilogue: reduce il, logits, pred, class loss ----
  red_s[tid] = il;
  __syncthreads();
  for (int k = 256; k > 0; k >>= 1) {
    if (tid < k) red_s[tid] += red_s[tid + k];
    __syncthreads();
  }
  if (tid == 0) atomicAdd(&ws_acc[0], red_s[0]);
  if (tid < 16) red16[tid] = 0.f;
  __syncthreads();
  if (isG) {
    #pragma unroll
    for (int q = 0; q < 4; ++q) atomicAdd(&red16[r4 * 4 + q], lacc[q]);
  }
  __syncthreads();

  if (tid < ROWS) {
    float lg = red16[tid] / (float)Tn + out_b[0];
    int rg = row0 + tid;
    float pred = sigf(lg);
    out[1 + (size_t)Bsz * Tn * Dn + rg] = pred;
    float y = label[rg], wt = is_train[rg];
    float bce = fmaxf(lg, 0.f) - lg * y + log1pf(__expf(-fabsf(lg)));
    atomicAdd(&ws_acc[1], bce * wt);
    atomicAdd(&ws_acc[2], wt);
  }
}

// ---------------- finalize loss -------------------------------------------------
__global__ void fin_k(const float* __restrict__ ws, float* __restrict__ out) {
  out[0] = ws[1] / (ws[2] + EPSf) + ws[0] / (float)Tn;
}

extern "C" void kernel_launch(void* const* d_in, const int* in_sizes, int n_in,
                              void* d_out, int out_size, void* d_ws, size_t ws_size,
                              hipStream_t stream) {
  const float* values   = (const float*)d_in[0];
  const float* masks    = (const float*)d_in[1];
  const float* deltas   = (const float*)d_in[2];
  const float* label    = (const float*)d_in[3];
  const float* is_train = (const float*)d_in[4];
  const float* W_ih     = (const float*)d_in[5];
  const float* W_hh     = (const float*)d_in[6];
  const float* b_ih     = (const float*)d_in[7];
  const float* b_hh     = (const float*)d_in[8];
  const float* hist_W   = (const float*)d_in[9];
  const float* hist_b   = (const float*)d_in[10];
  const float* feat_W   = (const float*)d_in[11];
  const float* feat_b   = (const float*)d_in[12];
  const float* decay_W  = (const float*)d_in[13];
  const float* decay_b  = (const float*)d_in[14];
  const float* comb_W   = (const float*)d_in[15];
  const float* comb_b   = (const float*)d_in[16];
  const float* out_W    = (const float*)d_in[17];
  const float* out_b    = (const float*)d_in[18];

  float* ws = (float*)d_ws;
  float* rmsum = ws + 4;
  float* out = (float*)d_out;

  hipMemsetAsync(d_ws, 0, 16, stream);
  msum_k<<<Tn, 256, 0, stream>>>((const float4*)masks, rmsum);
  brits_main<<<Bsz / ROWS, 512, 0, stream>>>(
      values, masks, deltas, label, is_train, W_ih, W_hh, b_ih, b_hh,
      hist_W, hist_b, feat_W, feat_b, decay_W, decay_b, comb_W, comb_b,
      out_W, out_b, out, rmsum, ws);
  fin_k<<<1, 1, 0, stream>>>(ws, out);
}